// Round 7
// baseline (407.519 us; speedup 1.0000x reference)
//
#include <hip/hip_runtime.h>

#define NB_ 16   // batch
#define S_ 512
#define D_ 768
#define H_ 12
#define DH_ 64
#define QT_ 64   // flash q-tile
#define KT_ 128  // flash k-tile

typedef __attribute__((ext_vector_type(8))) short bf16x8;
typedef __attribute__((ext_vector_type(4))) float f32x4;
typedef unsigned short ushort_t;

__device__ __forceinline__ unsigned short f2bf(float f){
  unsigned int u = __float_as_uint(f);
  u += 0x7fffu + ((u >> 16) & 1u);   // round-to-nearest-even
  return (unsigned short)(u >> 16);
}
__device__ __forceinline__ float bf2f(unsigned short s){
  return __uint_as_float(((unsigned int)s) << 16);
}
__device__ __forceinline__ unsigned int pack2(float a, float b){
  return (unsigned int)f2bf(a) | ((unsigned int)f2bf(b) << 16);
}
// async global->LDS, 16B per lane. LDS side must be uniform-base + lane*16.
__device__ __forceinline__ void gld16(const ushort_t* g, ushort_t* l){
  __builtin_amdgcn_global_load_lds((const __attribute__((address_space(1))) unsigned int*)g,
                                   (__attribute__((address_space(3))) unsigned int*)l, 16, 0, 0);
}

// ---------------- weight transpose fp32[K][N] -> bf16[N][K] ----------------
__global__ __launch_bounds__(256) void k_wtrans(const float* __restrict__ W0, const float* __restrict__ W1,
                                                const float* __restrict__ W2, const float* __restrict__ W3,
                                                ushort_t* __restrict__ dst){
  const float* W = (blockIdx.z == 0) ? W0 : (blockIdx.z == 1) ? W1 : (blockIdx.z == 2) ? W2 : W3;
  ushort_t* o = dst + (size_t)blockIdx.z * D_ * D_;
  __shared__ float t[32][33];
  int j = threadIdx.x & 31, i0 = threadIdx.x >> 5;
  int kb = blockIdx.y * 32, nb = blockIdx.x * 32;
#pragma unroll
  for (int r = 0; r < 4; r++){
    int i = i0 + r * 8;
    t[i][j] = W[(size_t)(kb + i) * D_ + nb + j];
  }
  __syncthreads();
#pragma unroll
  for (int r = 0; r < 4; r++){
    int i = i0 + r * 8;
    o[(size_t)(nb + i) * D_ + kb + j] = f2bf(t[j][i]);
  }
}

// ---------------- concat bq|bk|bv -> [2304] ----------------
__global__ __launch_bounds__(256) void k_bias3(const float* __restrict__ b0, const float* __restrict__ b1,
                                               const float* __restrict__ b2, float* __restrict__ o){
  int i = blockIdx.x * 256 + threadIdx.x;
  if (i < 3 * D_){
    float v = (i < D_) ? b0[i] : (i < 2 * D_) ? b1[i - D_] : b2[i - 2 * D_];
    o[i] = v;
  }
}

// ---------------- fused hs->bf16 convert + pooled-gate stage 1 ----------------
__global__ __launch_bounds__(256) void k_prep(const float* __restrict__ hs, const float* __restrict__ mask,
                                              ushort_t* __restrict__ hsb,
                                              float* __restrict__ partial, float* __restrict__ pcnt){
  int chunk = blockIdx.x, b = blockIdx.y, tid = threadIdx.x;
  const float* mrow = mask + b * S_ + chunk * 64;
  const float* base = hs + ((size_t)b * S_ + chunk * 64) * D_;
  ushort_t* obase = hsb + ((size_t)b * S_ + chunk * 64) * D_;
  float a0 = 0.f, a1 = 0.f, a2 = 0.f, cnt = 0.f;
#pragma unroll 2
  for (int s = 0; s < 64; s++){
    const float* r = base + (size_t)s * D_;
    float x0 = r[tid], x1 = r[tid + 256], x2 = r[tid + 512];
    ushort_t* o = obase + (size_t)s * D_;
    o[tid] = f2bf(x0); o[tid + 256] = f2bf(x1); o[tid + 512] = f2bf(x2);
    if (mrow[s] == 0.0f){ a0 += x0; a1 += x1; a2 += x2; cnt += 1.0f; }
  }
  float* o = partial + (size_t)(b * 8 + chunk) * D_;
  o[tid] = a0; o[tid + 256] = a1; o[tid + 512] = a2;
  if (tid == 0) pcnt[b * 8 + chunk] = cnt;
}

// ---------------- pooled gate, stage 2 ----------------
__global__ __launch_bounds__(256) void k_pool2(const float* __restrict__ partial, const float* __restrict__ pcnt,
                                               const float* __restrict__ Wg, const float* __restrict__ bg,
                                               float* __restrict__ gate){
  int b = blockIdx.x, tid = threadIdx.x;
  __shared__ float red[256];
  __shared__ float hp[768];
  float a0 = 0.f, a1 = 0.f, a2 = 0.f;
#pragma unroll
  for (int c = 0; c < 8; c++){
    const float* p = partial + (size_t)(b * 8 + c) * D_;
    a0 += p[tid]; a1 += p[tid + 256]; a2 += p[tid + 512];
  }
  float denom = 0.f;
#pragma unroll
  for (int c = 0; c < 8; c++) denom += pcnt[b * 8 + c];
  float inv = 1.0f / fmaxf(denom, 1.0f);
  hp[tid] = a0 * inv; hp[tid + 256] = a1 * inv; hp[tid + 512] = a2 * inv;
  __syncthreads();
  float p0 = 0.f, p1 = 0.f;
  for (int d = tid; d < D_; d += 256){ p0 += hp[d] * Wg[d * 2]; p1 += hp[d] * Wg[d * 2 + 1]; }
  red[tid] = p0; __syncthreads();
  for (int o = 128; o > 0; o >>= 1){ if (tid < o) red[tid] += red[tid + o]; __syncthreads(); }
  float z0 = red[0]; __syncthreads();
  red[tid] = p1; __syncthreads();
  for (int o = 128; o > 0; o >>= 1){ if (tid < o) red[tid] += red[tid + o]; __syncthreads(); }
  float z1 = red[0];
  if (tid == 0){
    z0 = (z0 + bg[0]) * 0.5f; z1 = (z1 + bg[1]) * 0.5f;
    float m = fmaxf(z0, z1);
    float e0 = __expf(z0 - m), e1 = __expf(z1 - m);
    float ssum = e0 + e1;
    gate[b * 2] = e0 / ssum; gate[b * 2 + 1] = e1 / ssum;
  }
}

// ---------------- BT GEMM (128x128 tile, BK=64, swizzled LDS, global_load_lds) ----------
// MAP 0: (bx=n, by=m, bz=z) | MAP 1: (bx=m, by=n) XCD-local same-m | MAP 2: (bx=z, by=m, bz=n).
template<int OUTBF16, int RELU, int RESID, int AFP32, int MAP>
__global__ __launch_bounds__(256) void k_gemm_bt(
    const void* __restrict__ Ap, long sA, int lda,
    const ushort_t* __restrict__ Bm, long sB, int ldb,
    void* __restrict__ Cp, long sC, int ldc,
    const float* __restrict__ bias,
    const float* __restrict__ resid, float alpha, int K)
{
  __shared__ ushort_t As[128 * 64];
  __shared__ ushort_t Bs[128 * 64];
  int z, bm, bn;
  if (MAP == 2){ z = blockIdx.x; bm = blockIdx.y; bn = blockIdx.z; }
  else if (MAP == 1){ z = blockIdx.z; bm = blockIdx.x; bn = blockIdx.y; }
  else { z = blockIdx.z; bm = blockIdx.y; bn = blockIdx.x; }
  const ushort_t* Ab = AFP32 ? nullptr : ((const ushort_t*)Ap + (size_t)z * sA);
  const float*    Af = AFP32 ? ((const float*)Ap + (size_t)z * sA) : nullptr;
  const ushort_t* Bb = Bm + (size_t)z * sB;
  const long coff = (long)z * sC;
  const int tid = threadIdx.x;
  const int m0 = bm * 128, n0 = bn * 128;
  const int wid = tid >> 6, lane = tid & 63;
  const int quad = lane >> 4, l16 = lane & 15;
  const int wm = wid >> 1, wn = wid & 1;
  const int sw = l16 & 7;                 // fragment-read swizzle (row-local)

  f32x4 acc[4][4];
#pragma unroll
  for (int i = 0; i < 4; i++)
#pragma unroll
    for (int j = 0; j < 4; j++) acc[i][j] = (f32x4){0.f, 0.f, 0.f, 0.f};

  for (int k0 = 0; k0 < K; k0 += 64){
#pragma unroll
    for (int c = 0; c < 4; c++){
      int idx = tid + c * 256;            // 1024 chunks: row = idx>>3, pos = idx&7
      int row = idx >> 3, p = idx & 7;
      int cg = p ^ (row & 7);
      if (AFP32){
        const float* src = Af + (size_t)(m0 + row) * lda + k0 + cg * 8;
        float4 f0 = *(const float4*)src;
        float4 f1 = *(const float4*)(src + 4);
        uint4 pk;
        pk.x = pack2(f0.x, f0.y);
        pk.y = pack2(f0.z, f0.w);
        pk.z = pack2(f1.x, f1.y);
        pk.w = pack2(f1.z, f1.w);
        *(uint4*)(&As[idx * 8]) = pk;
      } else {
        gld16(Ab + (size_t)(m0 + row) * lda + k0 + cg * 8, &As[idx * 8]);
      }
    }
#pragma unroll
    for (int c = 0; c < 4; c++){
      int idx = tid + c * 256;
      int row = idx >> 3, p = idx & 7;
      int cg = p ^ (row & 7);
      gld16(Bb + (size_t)(n0 + row) * ldb + k0 + cg * 8, &Bs[idx * 8]);
    }
    __syncthreads();
#pragma unroll
    for (int ks = 0; ks < 2; ks++){
      bf16x8 af[4], bfv[4];
#pragma unroll
      for (int mi = 0; mi < 4; mi++){
        int row = wm * 64 + mi * 16 + l16;
        af[mi] = *(const bf16x8*)(&As[(row * 8 + ((ks * 4 + quad) ^ sw)) * 8]);
      }
#pragma unroll
      for (int ni = 0; ni < 4; ni++){
        int row = wn * 64 + ni * 16 + l16;
        bfv[ni] = *(const bf16x8*)(&Bs[(row * 8 + ((ks * 4 + quad) ^ sw)) * 8]);
      }
#pragma unroll
      for (int mi = 0; mi < 4; mi++)
#pragma unroll
        for (int ni = 0; ni < 4; ni++)
          acc[mi][ni] = __builtin_amdgcn_mfma_f32_16x16x32_bf16(af[mi], bfv[ni], acc[mi][ni], 0, 0, 0);
    }
    __syncthreads();
  }

#pragma unroll
  for (int mi = 0; mi < 4; mi++){
#pragma unroll
    for (int ni = 0; ni < 4; ni++){
      int col = n0 + wn * 64 + ni * 16 + l16;
      float bcol = bias ? bias[col] : 0.0f;
#pragma unroll
      for (int r = 0; r < 4; r++){
        int row = m0 + wm * 64 + mi * 16 + quad * 4 + r;
        float v = acc[mi][ni][r] * alpha + bcol;
        if (RELU) v = fmaxf(v, 0.0f);
        if (RESID) v += resid[(size_t)row * ldc + col];
        long idx = coff + (long)row * ldc + col;
        if (OUTBF16) ((ushort_t*)Cp)[idx] = f2bf(v);
        else         ((float*)Cp)[idx] = v;
      }
    }
  }
}

// ---------------- per-head V transpose: vt[z][dh][t] = v[b,t,(voff)+h*64+dh] ----------------
__global__ __launch_bounds__(256) void k_vtrans(const ushort_t* __restrict__ v, int ldv,
                                                ushort_t* __restrict__ vt){
  __shared__ ushort_t t[64][66];
  int st = blockIdx.x * 64; int z = blockIdx.y;
  int b = z / H_, h = z - b * H_;
  int tid = threadIdx.x;
  const ushort_t* src = v + ((size_t)b * S_ + st) * ldv + h * DH_;
#pragma unroll
  for (int rep = 0; rep < 8; rep++){
    int idx = rep * 256 + tid;
    int i = idx >> 5, u = idx & 31;
    unsigned int val = *(const unsigned int*)(src + (size_t)i * ldv + u * 2);
    *(unsigned int*)(&t[i][u * 2]) = val;
  }
  __syncthreads();
  ushort_t* dst = vt + (size_t)z * DH_ * S_ + st;
#pragma unroll
  for (int rep = 0; rep < 8; rep++){
    int idx = rep * 256 + tid;
    int d = idx >> 5, u2 = idx & 31;
    unsigned int val = (unsigned int)t[u2 * 2][d] | ((unsigned int)t[u2 * 2 + 1][d] << 16);
    *(unsigned int*)(dst + (size_t)d * S_ + u2 * 2) = val;
  }
}

// ---------------- fused flash attention with prior blend ----------------
// Per-wave t-range partitioning: PV computed as O^T = V^T · P^T with P as the B
// operand (B-frag built from QK C-layout via same-l16 cross-quad shuffles — no LDS
// P round-trip, no mid-tile barrier). Per-wave partial O reduced once via LDS atomics
// into Obuf (reuses dead Ks space). grid (z, qtile) so same-z blocks share an XCD L2.
__global__ __launch_bounds__(256, 3) void k_flash(
    const ushort_t* __restrict__ qkv,      // [B*S][2304]; q at col 0, k at col 768
    const ushort_t* __restrict__ vt,       // [B*H][64][512]
    const ushort_t* __restrict__ priorctx, // [B*S][768] bf16
    const float* __restrict__ mask,        // [B][S]
    const float* __restrict__ gate,        // [B][2]
    ushort_t* __restrict__ ctx)            // [B*S][768]
{
  __shared__ ushort_t Qs[QT_ * 72];    // [q][dh], pad to 72
  __shared__ ushort_t Ks[KT_ * 72];    // [t][dh]  (reused as Obuf in epilogue)
  __shared__ ushort_t Vs[DH_ * 136];   // [dh][t], pad to 136
  __shared__ float rs[QT_];
  float* Obuf = (float*)Ks;            // [64][65] fp32 = 16.6 KB <= 18.4 KB
  const int z = blockIdx.x, b = z / H_, h = z - b * H_;
  const int q0 = blockIdx.y * QT_;
  const int tid = threadIdx.x;
  const int wid = tid >> 6, lane = tid & 63, quad = lane >> 4, l16 = lane & 15;

  // stage Q tile (64 x 64)
#pragma unroll
  for (int i = 0; i < 2; i++){
    int c = tid + i * 256;
    int row = c >> 3, off = (c & 7) * 8;
    *(float4*)(&Qs[row * 72 + off]) =
      *(const float4*)(qkv + ((size_t)(b * S_ + q0 + row)) * 2304 + h * DH_ + off);
  }

  f32x4 accO[4][4];                    // [dh-tile][q-tile], partial over this wave's t
#pragma unroll
  for (int mi = 0; mi < 4; mi++)
#pragma unroll
    for (int ni = 0; ni < 4; ni++) accO[mi][ni] = (f32x4){0.f, 0.f, 0.f, 0.f};
  float Lacc[4] = {0.f, 0.f, 0.f, 0.f};

  for (int t0 = 0; t0 < S_; t0 += KT_){
    if (mask[b * S_ + t0] != 0.0f) break;   // monotone pad mask: whole tile -> exp 0
    // stage K tile (128 x 64) and V^T tile (64 x 128)
#pragma unroll
    for (int i = 0; i < 4; i++){
      int c = tid + i * 256;
      int row = c >> 3, off = (c & 7) * 8;
      *(float4*)(&Ks[row * 72 + off]) =
        *(const float4*)(qkv + ((size_t)(b * S_ + t0 + row)) * 2304 + D_ + h * DH_ + off);
    }
#pragma unroll
    for (int i = 0; i < 4; i++){
      int c = tid + i * 256;
      int row = c >> 4, off = (c & 15) * 8;
      *(float4*)(&Vs[row * 136 + off]) =
        *(const float4*)(vt + (size_t)z * (DH_ * S_) + (size_t)row * S_ + t0 + off);
    }
    __syncthreads();

    // S^T = K·Q^T for this wave's t-range [wid*32, wid*32+32): m=t(2 tiles), n=q(4), k=dh 64
    f32x4 accs[2][4];
#pragma unroll
    for (int mi = 0; mi < 2; mi++)
#pragma unroll
      for (int ni = 0; ni < 4; ni++) accs[mi][ni] = (f32x4){0.f, 0.f, 0.f, 0.f};
#pragma unroll
    for (int ks = 0; ks < 2; ks++){
      bf16x8 ak[2], bq[4];
#pragma unroll
      for (int mi = 0; mi < 2; mi++)
        ak[mi] = *(const bf16x8*)(&Ks[(wid * 32 + mi * 16 + l16) * 72 + ks * 32 + quad * 8]);
#pragma unroll
      for (int ni = 0; ni < 4; ni++)
        bq[ni] = *(const bf16x8*)(&Qs[(ni * 16 + l16) * 72 + ks * 32 + quad * 8]);
#pragma unroll
      for (int mi = 0; mi < 2; mi++)
#pragma unroll
        for (int ni = 0; ni < 4; ni++)
          accs[mi][ni] = __builtin_amdgcn_mfma_f32_16x16x32_bf16(ak[mi], bq[ni], accs[mi][ni], 0, 0, 0);
    }

    // exp + pack (bf16 pairs) + per-lane rowsum accumulation
    float mv[2][4];
#pragma unroll
    for (int mi = 0; mi < 2; mi++)
#pragma unroll
      for (int r = 0; r < 4; r++)
        mv[mi][r] = mask[b * S_ + t0 + wid * 32 + mi * 16 + quad * 4 + r];
    unsigned int u[2][4][2];
#pragma unroll
    for (int mi = 0; mi < 2; mi++){
#pragma unroll
      for (int ni = 0; ni < 4; ni++){
        float e0 = __expf(accs[mi][ni][0] * 0.125f + mv[mi][0]);
        float e1 = __expf(accs[mi][ni][1] * 0.125f + mv[mi][1]);
        float e2 = __expf(accs[mi][ni][2] * 0.125f + mv[mi][2]);
        float e3 = __expf(accs[mi][ni][3] * 0.125f + mv[mi][3]);
        Lacc[ni] += (e0 + e1) + (e2 + e3);
        u[mi][ni][0] = pack2(e0, e1);
        u[mi][ni][1] = pack2(e2, e3);
      }
    }

    // PV partial: O^T += V^T · P^T over this wave's 32 t.
    // B-frag (n=q=l16, k=t=quad*8+j) gathered from C-layout via cross-quad shuffles.
    const int lsA = (2 * (quad & 1)) * 16 + l16;
    const int lsB = lsA + 16;
    bf16x8 aV[4];
#pragma unroll
    for (int mi = 0; mi < 4; mi++)
      aV[mi] = *(const bf16x8*)(&Vs[(mi * 16 + l16) * 136 + wid * 32 + quad * 8]);
#pragma unroll
    for (int ni = 0; ni < 4; ni++){
      int s00 = __shfl((int)u[0][ni][0], lsA), s01 = __shfl((int)u[0][ni][1], lsA);
      int s02 = __shfl((int)u[0][ni][0], lsB), s03 = __shfl((int)u[0][ni][1], lsB);
      int s10 = __shfl((int)u[1][ni][0], lsA), s11 = __shfl((int)u[1][ni][1], lsA);
      int s12 = __shfl((int)u[1][ni][0], lsB), s13 = __shfl((int)u[1][ni][1], lsB);
      uint4 fr;
      fr.x = (quad < 2) ? (unsigned int)s00 : (unsigned int)s10;
      fr.y = (quad < 2) ? (unsigned int)s01 : (unsigned int)s11;
      fr.z = (quad < 2) ? (unsigned int)s02 : (unsigned int)s12;
      fr.w = (quad < 2) ? (unsigned int)s03 : (unsigned int)s13;
      bf16x8 pf = *(bf16x8*)&fr;
#pragma unroll
      for (int mi = 0; mi < 4; mi++)
        accO[mi][ni] = __builtin_amdgcn_mfma_f32_16x16x32_bf16(aV[mi], pf, accO[mi][ni], 0, 0, 0);
    }
    __syncthreads();
  }

  // epilogue: zero Obuf (reuses Ks) + rs, reduce wave partials via LDS atomics
  for (int i = tid; i < 64 * 65; i += 256) Obuf[i] = 0.0f;
  if (tid < QT_) rs[tid] = 0.0f;
  __syncthreads();
#pragma unroll
  for (int ni = 0; ni < 4; ni++){
    float L = Lacc[ni];
    L += __shfl_xor(L, 16);
    L += __shfl_xor(L, 32);
    if (lane < 16) atomicAdd(&rs[ni * 16 + l16], L);
  }
#pragma unroll
  for (int mi = 0; mi < 4; mi++)
#pragma unroll
    for (int ni = 0; ni < 4; ni++)
#pragma unroll
      for (int r = 0; r < 4; r++)
        atomicAdd(&Obuf[(ni * 16 + l16) * 65 + mi * 16 + quad * 4 + r], accO[mi][ni][r]);
  __syncthreads();

  // blend + store: thread -> (q = tid>>2, 16 dh)
  const float g0 = gate[b * 2], g1 = gate[b * 2 + 1];
  int q = tid >> 2, dc = tid & 3;
  float scl = g0 / rs[q];
  size_t base = ((size_t)(b * S_ + q0 + q)) * D_ + h * DH_ + dc * 16;
#pragma unroll
  for (int p = 0; p < 8; p++){
    float v0 = Obuf[q * 65 + dc * 16 + p * 2] * scl;
    float v1 = Obuf[q * 65 + dc * 16 + p * 2 + 1] * scl;
    unsigned int pc = *(const unsigned int*)(priorctx + base + p * 2);
    v0 += g1 * bf2f((unsigned short)(pc & 0xffffu));
    v1 += g1 * bf2f((unsigned short)(pc >> 16));
    *(unsigned int*)(ctx + base + p * 2) = pack2(v0, v1);
  }
}

// ---------------- in-place LayerNorm over D=768 ----------------
__global__ __launch_bounds__(256) void k_ln(float* __restrict__ out, const float* __restrict__ gamma,
                                            const float* __restrict__ beta){
  __shared__ float red[256];
  int row = blockIdx.x, tid = threadIdx.x;
  float* p = out + (size_t)row * D_;
  float x0 = p[tid], x1 = p[tid + 256], x2 = p[tid + 512];
  red[tid] = x0 + x1 + x2; __syncthreads();
  for (int o = 128; o > 0; o >>= 1){ if (tid < o) red[tid] += red[tid + o]; __syncthreads(); }
  float mu = red[0] * (1.0f / 768.0f);
  __syncthreads();
  float d0 = x0 - mu, d1 = x1 - mu, d2 = x2 - mu;
  red[tid] = d0 * d0 + d1 * d1 + d2 * d2; __syncthreads();
  for (int o = 128; o > 0; o >>= 1){ if (tid < o) red[tid] += red[tid + o]; __syncthreads(); }
  float rsv = rsqrtf(red[0] * (1.0f / 768.0f) + 1e-5f);
  p[tid]       = d0 * rsv * gamma[tid]       + beta[tid];
  p[tid + 256] = d1 * rsv * gamma[tid + 256] + beta[tid + 256];
  p[tid + 512] = d2 * rsv * gamma[tid + 512] + beta[tid + 512];
}

extern "C" void kernel_launch(void* const* d_in, const int* in_sizes, int n_in,
                              void* d_out, int out_size, void* d_ws, size_t ws_size,
                              hipStream_t stream){
  const float* hs    = (const float*)d_in[0];
  const float* mask  = (const float*)d_in[1];
  const float* prior = (const float*)d_in[2];
  const float* Wq = (const float*)d_in[3];  const float* bq = (const float*)d_in[4];
  const float* Wk = (const float*)d_in[5];  const float* bk = (const float*)d_in[6];
  const float* Wv = (const float*)d_in[7];  const float* bv = (const float*)d_in[8];
  const float* Wg = (const float*)d_in[9];  const float* bg = (const float*)d_in[10];
  const float* Wo = (const float*)d_in[11]; const float* bo = (const float*)d_in[12];
  const float* gamma = (const float*)d_in[13]; const float* beta = (const float*)d_in[14];
  float* out = (float*)d_out;

  size_t off = 0;
  auto alloc = [&](size_t bytes) -> char* {
    char* p = (char*)d_ws + off;
    off += (bytes + 255) & ~(size_t)255;
    return p;
  };
  const size_t HSD = (size_t)NB_ * S_ * D_;            // 6.29M elems
  ushort_t* hsb     = (ushort_t*)alloc(HSD * 2);
  ushort_t* qkvb    = (ushort_t*)alloc(HSD * 3 * 2);   // [B*S][2304]
  ushort_t* vtb     = (ushort_t*)alloc(HSD * 2);       // [B*H][64][512]
  ushort_t* wt      = (ushort_t*)alloc((size_t)4 * D_ * D_ * 2);
  ushort_t* priorctx= (ushort_t*)alloc(HSD * 2);
  ushort_t* ctx     = (ushort_t*)alloc(HSD * 2);
  float*    bqkv    = (float*)alloc((size_t)3 * D_ * 4);
  float*    gate    = (float*)alloc(256);
  float*    partial = (float*)alloc((size_t)NB_ * 8 * D_ * 4);
  float*    pcnt    = (float*)alloc((size_t)NB_ * 8 * 4);

  // 1. converts / packs (hs convert fused with pool stage-1)
  k_prep<<<dim3(8, NB_), 256, 0, stream>>>(hs, mask, hsb, partial, pcnt);
  k_wtrans<<<dim3(24, 24, 4), 256, 0, stream>>>(Wq, Wk, Wv, Wo, wt);
  k_bias3<<<dim3(9), 256, 0, stream>>>(bq, bk, bv, bqkv);
  // 2. gate
  k_pool2<<<dim3(NB_), 256, 0, stream>>>(partial, pcnt, Wg, bg, gate);
  // 3. fused QKV projection: [8192x768] x [2304x768]^T -> [8192][2304] (MAP1: same-m -> same XCD)
  k_gemm_bt<1, 0, 0, 0, 1><<<dim3(64, 18, 1), 256, 0, stream>>>(
      hsb, 0, D_, wt, 0, D_, qkvb, 0, 3 * D_, bqkv, nullptr, 1.0f, D_);
  // 4. V transpose per head (v at col 1536 of qkvb)
  k_vtrans<<<dim3(S_ / 64, NB_ * H_), 256, 0, stream>>>(qkvb + 2 * D_, 3 * D_, vtb);
  // 5. priorctx = prior @ V (MAP2: same-batch -> same XCD; fp32 prior staged direct)
  k_gemm_bt<1, 0, 0, 1, 2><<<dim3(16, 4, 6), 256, 0, stream>>>(
      prior, (long)S_ * S_, S_, vtb, (long)H_ * DH_ * S_, S_,
      priorctx, (long)S_ * D_, D_, nullptr, nullptr, 1.0f, S_);
  // 6. flash attention + prior blend -> ctx (bf16); grid x=z so same-z -> same XCD
  k_flash<<<dim3(NB_ * H_, S_ / QT_), 256, 0, stream>>>(
      qkvb, vtb, priorctx, mask, gate, ctx);
  // 7. out = relu(ctx·Wo + bo) + hs  (fp32 into d_out)
  k_gemm_bt<0, 1, 1, 0, 1><<<dim3(64, 6, 1), 256, 0, stream>>>(
      ctx, 0, D_, wt + 3 * (size_t)D_ * D_, 0, D_, out, 0, D_, bo, hs, 1.0f, D_);
  // 8. LayerNorm in place on d_out
  k_ln<<<dim3(NB_ * S_), 256, 0, stream>>>(out, gamma, beta);
}

// Round 8
// 300.272 us; speedup vs baseline: 1.3572x; 1.3572x over previous
//
#include <hip/hip_runtime.h>

#define NB_ 16   // batch
#define S_ 512
#define D_ 768
#define H_ 12
#define DH_ 64
#define QT_ 64   // flash q-tile
#define KT_ 128  // flash k-tile

typedef __attribute__((ext_vector_type(8))) short bf16x8;
typedef __attribute__((ext_vector_type(4))) float f32x4;
typedef unsigned short ushort_t;

__device__ __forceinline__ unsigned short f2bf(float f){
  unsigned int u = __float_as_uint(f);
  u += 0x7fffu + ((u >> 16) & 1u);   // round-to-nearest-even
  return (unsigned short)(u >> 16);
}
__device__ __forceinline__ float bf2f(unsigned short s){
  return __uint_as_float(((unsigned int)s) << 16);
}
__device__ __forceinline__ unsigned int pack2(float a, float b){
  return (unsigned int)f2bf(a) | ((unsigned int)f2bf(b) << 16);
}
// async global->LDS, 16B per lane. LDS side must be uniform-base + lane*16.
__device__ __forceinline__ void gld16(const ushort_t* g, ushort_t* l){
  __builtin_amdgcn_global_load_lds((const __attribute__((address_space(1))) unsigned int*)g,
                                   (__attribute__((address_space(3))) unsigned int*)l, 16, 0, 0);
}

// ---------------- weight transpose fp32[K][N] -> bf16[N][K] ----------------
__global__ __launch_bounds__(256) void k_wtrans(const float* __restrict__ W0, const float* __restrict__ W1,
                                                const float* __restrict__ W2, const float* __restrict__ W3,
                                                ushort_t* __restrict__ dst){
  const float* W = (blockIdx.z == 0) ? W0 : (blockIdx.z == 1) ? W1 : (blockIdx.z == 2) ? W2 : W3;
  ushort_t* o = dst + (size_t)blockIdx.z * D_ * D_;
  __shared__ float t[32][33];
  int j = threadIdx.x & 31, i0 = threadIdx.x >> 5;
  int kb = blockIdx.y * 32, nb = blockIdx.x * 32;
#pragma unroll
  for (int r = 0; r < 4; r++){
    int i = i0 + r * 8;
    t[i][j] = W[(size_t)(kb + i) * D_ + nb + j];
  }
  __syncthreads();
#pragma unroll
  for (int r = 0; r < 4; r++){
    int i = i0 + r * 8;
    o[(size_t)(nb + i) * D_ + kb + j] = f2bf(t[j][i]);
  }
}

// ---------------- concat bq|bk|bv -> [2304] ----------------
__global__ __launch_bounds__(256) void k_bias3(const float* __restrict__ b0, const float* __restrict__ b1,
                                               const float* __restrict__ b2, float* __restrict__ o){
  int i = blockIdx.x * 256 + threadIdx.x;
  if (i < 3 * D_){
    float v = (i < D_) ? b0[i] : (i < 2 * D_) ? b1[i - D_] : b2[i - 2 * D_];
    o[i] = v;
  }
}

// ---------------- fused hs->bf16 convert + pooled-gate stage 1 ----------------
__global__ __launch_bounds__(256) void k_prep(const float* __restrict__ hs, const float* __restrict__ mask,
                                              ushort_t* __restrict__ hsb,
                                              float* __restrict__ partial, float* __restrict__ pcnt){
  int chunk = blockIdx.x, b = blockIdx.y, tid = threadIdx.x;
  const float* mrow = mask + b * S_ + chunk * 64;
  const float* base = hs + ((size_t)b * S_ + chunk * 64) * D_;
  ushort_t* obase = hsb + ((size_t)b * S_ + chunk * 64) * D_;
  float a0 = 0.f, a1 = 0.f, a2 = 0.f, cnt = 0.f;
#pragma unroll 2
  for (int s = 0; s < 64; s++){
    const float* r = base + (size_t)s * D_;
    float x0 = r[tid], x1 = r[tid + 256], x2 = r[tid + 512];
    ushort_t* o = obase + (size_t)s * D_;
    o[tid] = f2bf(x0); o[tid + 256] = f2bf(x1); o[tid + 512] = f2bf(x2);
    if (mrow[s] == 0.0f){ a0 += x0; a1 += x1; a2 += x2; cnt += 1.0f; }
  }
  float* o = partial + (size_t)(b * 8 + chunk) * D_;
  o[tid] = a0; o[tid + 256] = a1; o[tid + 512] = a2;
  if (tid == 0) pcnt[b * 8 + chunk] = cnt;
}

// ---------------- pooled gate, stage 2 ----------------
__global__ __launch_bounds__(256) void k_pool2(const float* __restrict__ partial, const float* __restrict__ pcnt,
                                               const float* __restrict__ Wg, const float* __restrict__ bg,
                                               float* __restrict__ gate){
  int b = blockIdx.x, tid = threadIdx.x;
  __shared__ float red[256];
  __shared__ float hp[768];
  float a0 = 0.f, a1 = 0.f, a2 = 0.f;
#pragma unroll
  for (int c = 0; c < 8; c++){
    const float* p = partial + (size_t)(b * 8 + c) * D_;
    a0 += p[tid]; a1 += p[tid + 256]; a2 += p[tid + 512];
  }
  float denom = 0.f;
#pragma unroll
  for (int c = 0; c < 8; c++) denom += pcnt[b * 8 + c];
  float inv = 1.0f / fmaxf(denom, 1.0f);
  hp[tid] = a0 * inv; hp[tid + 256] = a1 * inv; hp[tid + 512] = a2 * inv;
  __syncthreads();
  float p0 = 0.f, p1 = 0.f;
  for (int d = tid; d < D_; d += 256){ p0 += hp[d] * Wg[d * 2]; p1 += hp[d] * Wg[d * 2 + 1]; }
  red[tid] = p0; __syncthreads();
  for (int o = 128; o > 0; o >>= 1){ if (tid < o) red[tid] += red[tid + o]; __syncthreads(); }
  float z0 = red[0]; __syncthreads();
  red[tid] = p1; __syncthreads();
  for (int o = 128; o > 0; o >>= 1){ if (tid < o) red[tid] += red[tid + o]; __syncthreads(); }
  float z1 = red[0];
  if (tid == 0){
    z0 = (z0 + bg[0]) * 0.5f; z1 = (z1 + bg[1]) * 0.5f;
    float m = fmaxf(z0, z1);
    float e0 = __expf(z0 - m), e1 = __expf(z1 - m);
    float ssum = e0 + e1;
    gate[b * 2] = e0 / ssum; gate[b * 2 + 1] = e1 / ssum;
  }
}

// ---------------- BT GEMM (128x128 tile, BK=64, swizzled LDS, global_load_lds) ----------
// MAP 0: (bx=n, by=m, bz=z) | MAP 1: (bx=m, by=n) XCD-local same-m | MAP 2: (bx=z, by=m, bz=n).
template<int OUTBF16, int RELU, int RESID, int AFP32, int MAP>
__global__ __launch_bounds__(256) void k_gemm_bt(
    const void* __restrict__ Ap, long sA, int lda,
    const ushort_t* __restrict__ Bm, long sB, int ldb,
    void* __restrict__ Cp, long sC, int ldc,
    const float* __restrict__ bias,
    const float* __restrict__ resid, float alpha, int K)
{
  __shared__ ushort_t As[128 * 64];
  __shared__ ushort_t Bs[128 * 64];
  int z, bm, bn;
  if (MAP == 2){ z = blockIdx.x; bm = blockIdx.y; bn = blockIdx.z; }
  else if (MAP == 1){ z = blockIdx.z; bm = blockIdx.x; bn = blockIdx.y; }
  else { z = blockIdx.z; bm = blockIdx.y; bn = blockIdx.x; }
  const ushort_t* Ab = AFP32 ? nullptr : ((const ushort_t*)Ap + (size_t)z * sA);
  const float*    Af = AFP32 ? ((const float*)Ap + (size_t)z * sA) : nullptr;
  const ushort_t* Bb = Bm + (size_t)z * sB;
  const long coff = (long)z * sC;
  const int tid = threadIdx.x;
  const int m0 = bm * 128, n0 = bn * 128;
  const int wid = tid >> 6, lane = tid & 63;
  const int quad = lane >> 4, l16 = lane & 15;
  const int wm = wid >> 1, wn = wid & 1;
  const int sw = l16 & 7;                 // fragment-read swizzle (row-local)

  f32x4 acc[4][4];
#pragma unroll
  for (int i = 0; i < 4; i++)
#pragma unroll
    for (int j = 0; j < 4; j++) acc[i][j] = (f32x4){0.f, 0.f, 0.f, 0.f};

  for (int k0 = 0; k0 < K; k0 += 64){
#pragma unroll
    for (int c = 0; c < 4; c++){
      int idx = tid + c * 256;            // 1024 chunks: row = idx>>3, pos = idx&7
      int row = idx >> 3, p = idx & 7;
      int cg = p ^ (row & 7);
      if (AFP32){
        const float* src = Af + (size_t)(m0 + row) * lda + k0 + cg * 8;
        float4 f0 = *(const float4*)src;
        float4 f1 = *(const float4*)(src + 4);
        uint4 pk;
        pk.x = pack2(f0.x, f0.y);
        pk.y = pack2(f0.z, f0.w);
        pk.z = pack2(f1.x, f1.y);
        pk.w = pack2(f1.z, f1.w);
        *(uint4*)(&As[idx * 8]) = pk;
      } else {
        gld16(Ab + (size_t)(m0 + row) * lda + k0 + cg * 8, &As[idx * 8]);
      }
    }
#pragma unroll
    for (int c = 0; c < 4; c++){
      int idx = tid + c * 256;
      int row = idx >> 3, p = idx & 7;
      int cg = p ^ (row & 7);
      gld16(Bb + (size_t)(n0 + row) * ldb + k0 + cg * 8, &Bs[idx * 8]);
    }
    __syncthreads();
#pragma unroll
    for (int ks = 0; ks < 2; ks++){
      bf16x8 af[4], bfv[4];
#pragma unroll
      for (int mi = 0; mi < 4; mi++){
        int row = wm * 64 + mi * 16 + l16;
        af[mi] = *(const bf16x8*)(&As[(row * 8 + ((ks * 4 + quad) ^ sw)) * 8]);
      }
#pragma unroll
      for (int ni = 0; ni < 4; ni++){
        int row = wn * 64 + ni * 16 + l16;
        bfv[ni] = *(const bf16x8*)(&Bs[(row * 8 + ((ks * 4 + quad) ^ sw)) * 8]);
      }
#pragma unroll
      for (int mi = 0; mi < 4; mi++)
#pragma unroll
        for (int ni = 0; ni < 4; ni++)
          acc[mi][ni] = __builtin_amdgcn_mfma_f32_16x16x32_bf16(af[mi], bfv[ni], acc[mi][ni], 0, 0, 0);
    }
    __syncthreads();
  }

#pragma unroll
  for (int mi = 0; mi < 4; mi++){
#pragma unroll
    for (int ni = 0; ni < 4; ni++){
      int col = n0 + wn * 64 + ni * 16 + l16;
      float bcol = bias ? bias[col] : 0.0f;
#pragma unroll
      for (int r = 0; r < 4; r++){
        int row = m0 + wm * 64 + mi * 16 + quad * 4 + r;
        float v = acc[mi][ni][r] * alpha + bcol;
        if (RELU) v = fmaxf(v, 0.0f);
        if (RESID) v += resid[(size_t)row * ldc + col];
        long idx = coff + (long)row * ldc + col;
        if (OUTBF16) ((ushort_t*)Cp)[idx] = f2bf(v);
        else         ((float*)Cp)[idx] = v;
      }
    }
  }
}

// ---------------- per-head V transpose: vt[z][dh][t] = v[b,t,(voff)+h*64+dh] ----------------
__global__ __launch_bounds__(256) void k_vtrans(const ushort_t* __restrict__ v, int ldv,
                                                ushort_t* __restrict__ vt){
  __shared__ ushort_t t[64][66];
  int st = blockIdx.x * 64; int z = blockIdx.y;
  int b = z / H_, h = z - b * H_;
  int tid = threadIdx.x;
  const ushort_t* src = v + ((size_t)b * S_ + st) * ldv + h * DH_;
#pragma unroll
  for (int rep = 0; rep < 8; rep++){
    int idx = rep * 256 + tid;
    int i = idx >> 5, u = idx & 31;
    unsigned int val = *(const unsigned int*)(src + (size_t)i * ldv + u * 2);
    *(unsigned int*)(&t[i][u * 2]) = val;
  }
  __syncthreads();
  ushort_t* dst = vt + (size_t)z * DH_ * S_ + st;
#pragma unroll
  for (int rep = 0; rep < 8; rep++){
    int idx = rep * 256 + tid;
    int d = idx >> 5, u2 = idx & 31;
    unsigned int val = (unsigned int)t[u2 * 2][d] | ((unsigned int)t[u2 * 2 + 1][d] << 16);
    *(unsigned int*)(dst + (size_t)d * S_ + u2 * 2) = val;
  }
}

// ---------------- fused flash attention with prior blend (R6 structure) ----------------
// grid (x=z, y=qtile): same-z blocks land on one XCD (z-stride 192 ≡ 0 mod 8) so K/V
// tiles are L2-served after first touch. Monotone pad-mask tail-skip per k-tile.
__global__ __launch_bounds__(256) void k_flash(
    const ushort_t* __restrict__ qkv,      // [B*S][2304]; q at col 0, k at col 768
    const ushort_t* __restrict__ vt,       // [B*H][64][512]
    const ushort_t* __restrict__ priorctx, // [B*S][768] bf16
    const float* __restrict__ mask,        // [B][S]
    const float* __restrict__ gate,        // [B][2]
    ushort_t* __restrict__ ctx)            // [B*S][768]
{
  __shared__ ushort_t Qs[QT_ * 72];    // [q][dh], pad to 72
  __shared__ ushort_t Ks[KT_ * 72];    // [t][dh]
  __shared__ ushort_t Vs[DH_ * 136];   // [dh][t], pad to 136
  __shared__ ushort_t Ps[QT_ * 136];   // [q][t]
  __shared__ float rs[QT_];
  const int z = blockIdx.x, b = z / H_, h = z - b * H_;
  const int q0 = blockIdx.y * QT_;
  const int tid = threadIdx.x;
  const int wid = tid >> 6, lane = tid & 63, quad = lane >> 4, l16 = lane & 15;

  // stage Q tile (64 x 64)
#pragma unroll
  for (int i = 0; i < 2; i++){
    int c = tid + i * 256;
    int row = c >> 3, off = (c & 7) * 8;
    *(float4*)(&Qs[row * 72 + off]) =
      *(const float4*)(qkv + ((size_t)(b * S_ + q0 + row)) * 2304 + h * DH_ + off);
  }
  if (tid < QT_) rs[tid] = 0.f;

  f32x4 accv[4];
#pragma unroll
  for (int ni = 0; ni < 4; ni++) accv[ni] = (f32x4){0.f, 0.f, 0.f, 0.f};

  for (int t0 = 0; t0 < S_; t0 += KT_){
    if (mask[b * S_ + t0] != 0.0f) break;   // monotone pad mask: whole tile masked
    // stage K tile (128 x 64) and V^T tile (64 x 128)
#pragma unroll
    for (int i = 0; i < 4; i++){
      int c = tid + i * 256;
      int row = c >> 3, off = (c & 7) * 8;
      *(float4*)(&Ks[row * 72 + off]) =
        *(const float4*)(qkv + ((size_t)(b * S_ + t0 + row)) * 2304 + D_ + h * DH_ + off);
    }
#pragma unroll
    for (int i = 0; i < 4; i++){
      int c = tid + i * 256;
      int row = c >> 4, off = (c & 15) * 8;
      *(float4*)(&Vs[row * 136 + off]) =
        *(const float4*)(vt + (size_t)z * (DH_ * S_) + (size_t)row * S_ + t0 + off);
    }
    __syncthreads();

    // S^T = K·Q^T : A = K tokens (m, 128), B = Q rows (n, 64), k-dim = dh (64)
    f32x4 accs[2][4];
#pragma unroll
    for (int mi = 0; mi < 2; mi++)
#pragma unroll
      for (int ni = 0; ni < 4; ni++) accs[mi][ni] = (f32x4){0.f, 0.f, 0.f, 0.f};
    bf16x8 ak[2][2], bq[4][2];
#pragma unroll
    for (int mi = 0; mi < 2; mi++)
#pragma unroll
      for (int ks = 0; ks < 2; ks++)
        ak[mi][ks] = *(const bf16x8*)(&Ks[(wid * 32 + mi * 16 + l16) * 72 + ks * 32 + quad * 8]);
#pragma unroll
    for (int ni = 0; ni < 4; ni++)
#pragma unroll
      for (int ks = 0; ks < 2; ks++)
        bq[ni][ks] = *(const bf16x8*)(&Qs[(ni * 16 + l16) * 72 + ks * 32 + quad * 8]);
#pragma unroll
    for (int mi = 0; mi < 2; mi++)
#pragma unroll
      for (int ni = 0; ni < 4; ni++){
        accs[mi][ni] = __builtin_amdgcn_mfma_f32_16x16x32_bf16(ak[mi][0], bq[ni][0], accs[mi][ni], 0, 0, 0);
        accs[mi][ni] = __builtin_amdgcn_mfma_f32_16x16x32_bf16(ak[mi][1], bq[ni][1], accs[mi][ni], 0, 0, 0);
      }

    // exp + pack into Ps[q][t] (lane holds 4 contiguous t for fixed q) + row sums
    float mv[2][4];
#pragma unroll
    for (int mi = 0; mi < 2; mi++)
#pragma unroll
      for (int r = 0; r < 4; r++)
        mv[mi][r] = mask[b * S_ + t0 + wid * 32 + mi * 16 + quad * 4 + r];
    float rowpart[4] = {0.f, 0.f, 0.f, 0.f};
#pragma unroll
    for (int mi = 0; mi < 2; mi++){
#pragma unroll
      for (int ni = 0; ni < 4; ni++){
        float e0 = __expf(accs[mi][ni][0] * 0.125f + mv[mi][0]);
        float e1 = __expf(accs[mi][ni][1] * 0.125f + mv[mi][1]);
        float e2 = __expf(accs[mi][ni][2] * 0.125f + mv[mi][2]);
        float e3 = __expf(accs[mi][ni][3] * 0.125f + mv[mi][3]);
        rowpart[ni] += (e0 + e1) + (e2 + e3);
        uint2 pk;
        pk.x = pack2(e0, e1);
        pk.y = pack2(e2, e3);
        *(uint2*)(&Ps[(ni * 16 + l16) * 136 + wid * 32 + mi * 16 + quad * 4]) = pk;
      }
    }
#pragma unroll
    for (int ni = 0; ni < 4; ni++){
      rowpart[ni] += __shfl_xor(rowpart[ni], 16);
      rowpart[ni] += __shfl_xor(rowpart[ni], 32);
    }
    if (lane < 16){
#pragma unroll
      for (int ni = 0; ni < 4; ni++) atomicAdd(&rs[ni * 16 + l16], rowpart[ni]);
    }
    __syncthreads();

    // PV: A = Ps (m = q, this wave's 16 rows), B = Vs (n = dh), k = t (128)
#pragma unroll
    for (int ks = 0; ks < 4; ks++){
      bf16x8 ap = *(const bf16x8*)(&Ps[(wid * 16 + l16) * 136 + ks * 32 + quad * 8]);
#pragma unroll
      for (int ni = 0; ni < 4; ni++){
        bf16x8 bv8 = *(const bf16x8*)(&Vs[(ni * 16 + l16) * 136 + ks * 32 + quad * 8]);
        accv[ni] = __builtin_amdgcn_mfma_f32_16x16x32_bf16(ap, bv8, accv[ni], 0, 0, 0);
      }
    }
    __syncthreads();
  }

  const float g0 = gate[b * 2], g1 = gate[b * 2 + 1];
#pragma unroll
  for (int ni = 0; ni < 4; ni++){
#pragma unroll
    for (int r = 0; r < 4; r++){
      int q = wid * 16 + quad * 4 + r;
      int dh = ni * 16 + l16;
      float scl = g0 / rs[q];
      size_t idx = ((size_t)(b * S_ + q0 + q)) * D_ + h * DH_ + dh;
      float v = accv[ni][r] * scl + g1 * bf2f(priorctx[idx]);
      ctx[idx] = f2bf(v);
    }
  }
}

// ---------------- in-place LayerNorm over D=768 ----------------
__global__ __launch_bounds__(256) void k_ln(float* __restrict__ out, const float* __restrict__ gamma,
                                            const float* __restrict__ beta){
  __shared__ float red[256];
  int row = blockIdx.x, tid = threadIdx.x;
  float* p = out + (size_t)row * D_;
  float x0 = p[tid], x1 = p[tid + 256], x2 = p[tid + 512];
  red[tid] = x0 + x1 + x2; __syncthreads();
  for (int o = 128; o > 0; o >>= 1){ if (tid < o) red[tid] += red[tid + o]; __syncthreads(); }
  float mu = red[0] * (1.0f / 768.0f);
  __syncthreads();
  float d0 = x0 - mu, d1 = x1 - mu, d2 = x2 - mu;
  red[tid] = d0 * d0 + d1 * d1 + d2 * d2; __syncthreads();
  for (int o = 128; o > 0; o >>= 1){ if (tid < o) red[tid] += red[tid + o]; __syncthreads(); }
  float rsv = rsqrtf(red[0] * (1.0f / 768.0f) + 1e-5f);
  p[tid]       = d0 * rsv * gamma[tid]       + beta[tid];
  p[tid + 256] = d1 * rsv * gamma[tid + 256] + beta[tid + 256];
  p[tid + 512] = d2 * rsv * gamma[tid + 512] + beta[tid + 512];
}

extern "C" void kernel_launch(void* const* d_in, const int* in_sizes, int n_in,
                              void* d_out, int out_size, void* d_ws, size_t ws_size,
                              hipStream_t stream){
  const float* hs    = (const float*)d_in[0];
  const float* mask  = (const float*)d_in[1];
  const float* prior = (const float*)d_in[2];
  const float* Wq = (const float*)d_in[3];  const float* bq = (const float*)d_in[4];
  const float* Wk = (const float*)d_in[5];  const float* bk = (const float*)d_in[6];
  const float* Wv = (const float*)d_in[7];  const float* bv = (const float*)d_in[8];
  const float* Wg = (const float*)d_in[9];  const float* bg = (const float*)d_in[10];
  const float* Wo = (const float*)d_in[11]; const float* bo = (const float*)d_in[12];
  const float* gamma = (const float*)d_in[13]; const float* beta = (const float*)d_in[14];
  float* out = (float*)d_out;

  size_t off = 0;
  auto alloc = [&](size_t bytes) -> char* {
    char* p = (char*)d_ws + off;
    off += (bytes + 255) & ~(size_t)255;
    return p;
  };
  const size_t HSD = (size_t)NB_ * S_ * D_;            // 6.29M elems
  ushort_t* hsb     = (ushort_t*)alloc(HSD * 2);
  ushort_t* qkvb    = (ushort_t*)alloc(HSD * 3 * 2);   // [B*S][2304]
  ushort_t* vtb     = (ushort_t*)alloc(HSD * 2);       // [B*H][64][512]
  ushort_t* wt      = (ushort_t*)alloc((size_t)4 * D_ * D_ * 2);
  ushort_t* priorctx= (ushort_t*)alloc(HSD * 2);
  ushort_t* ctx     = (ushort_t*)alloc(HSD * 2);
  float*    bqkv    = (float*)alloc((size_t)3 * D_ * 4);
  float*    gate    = (float*)alloc(256);
  float*    partial = (float*)alloc((size_t)NB_ * 8 * D_ * 4);
  float*    pcnt    = (float*)alloc((size_t)NB_ * 8 * 4);

  // 1. converts / packs (hs convert fused with pool stage-1)
  k_prep<<<dim3(8, NB_), 256, 0, stream>>>(hs, mask, hsb, partial, pcnt);
  k_wtrans<<<dim3(24, 24, 4), 256, 0, stream>>>(Wq, Wk, Wv, Wo, wt);
  k_bias3<<<dim3(9), 256, 0, stream>>>(bq, bk, bv, bqkv);
  // 2. gate
  k_pool2<<<dim3(NB_), 256, 0, stream>>>(partial, pcnt, Wg, bg, gate);
  // 3. fused QKV projection: [8192x768] x [2304x768]^T -> [8192][2304] (MAP1: same-m -> same XCD)
  k_gemm_bt<1, 0, 0, 0, 1><<<dim3(64, 18, 1), 256, 0, stream>>>(
      hsb, 0, D_, wt, 0, D_, qkvb, 0, 3 * D_, bqkv, nullptr, 1.0f, D_);
  // 4. V transpose per head (v at col 1536 of qkvb)
  k_vtrans<<<dim3(S_ / 64, NB_ * H_), 256, 0, stream>>>(qkvb + 2 * D_, 3 * D_, vtb);
  // 5. priorctx = prior @ V (MAP2: same-batch -> same XCD; fp32 prior staged direct)
  k_gemm_bt<1, 0, 0, 1, 2><<<dim3(16, 4, 6), 256, 0, stream>>>(
      prior, (long)S_ * S_, S_, vtb, (long)H_ * DH_ * S_, S_,
      priorctx, (long)S_ * D_, D_, nullptr, nullptr, 1.0f, S_);
  // 6. flash attention + prior blend -> ctx (bf16); grid x=z so same-z -> same XCD
  k_flash<<<dim3(NB_ * H_, S_ / QT_), 256, 0, stream>>>(
      qkvb, vtb, priorctx, mask, gate, ctx);
  // 7. out = relu(ctx·Wo + bo) + hs  (fp32 into d_out)
  k_gemm_bt<0, 1, 1, 0, 1><<<dim3(64, 6, 1), 256, 0, stream>>>(
      ctx, 0, D_, wt + 3 * (size_t)D_ * D_, 0, D_, out, 0, D_, bo, hs, 1.0f, D_);
  // 8. LayerNorm in place on d_out
  k_ln<<<dim3(NB_ * S_), 256, 0, stream>>>(out, gamma, beta);
}

// Round 9
// 291.603 us; speedup vs baseline: 1.3975x; 1.0297x over previous
//
#include <hip/hip_runtime.h>

#define NB_ 16   // batch
#define S_ 512
#define D_ 768
#define H_ 12
#define DH_ 64
#define QT_ 64   // flash q-tile
#define KT_ 128  // flash k-tile

typedef __attribute__((ext_vector_type(8))) short bf16x8;
typedef __attribute__((ext_vector_type(4))) float f32x4;
typedef unsigned short ushort_t;

__device__ __forceinline__ unsigned short f2bf(float f){
  unsigned int u = __float_as_uint(f);
  u += 0x7fffu + ((u >> 16) & 1u);   // round-to-nearest-even
  return (unsigned short)(u >> 16);
}
__device__ __forceinline__ float bf2f(unsigned short s){
  return __uint_as_float(((unsigned int)s) << 16);
}
__device__ __forceinline__ unsigned int pack2(float a, float b){
  return (unsigned int)f2bf(a) | ((unsigned int)f2bf(b) << 16);
}
// async global->LDS, 16B per lane. LDS side must be uniform-base + lane*16.
__device__ __forceinline__ void gld16(const ushort_t* g, ushort_t* l){
  __builtin_amdgcn_global_load_lds((const __attribute__((address_space(1))) unsigned int*)g,
                                   (__attribute__((address_space(3))) unsigned int*)l, 16, 0, 0);
}

// ---------------- weight transpose fp32[K][N] -> bf16[N][K] ----------------
__global__ __launch_bounds__(256) void k_wtrans(const float* __restrict__ W0, const float* __restrict__ W1,
                                                const float* __restrict__ W2, const float* __restrict__ W3,
                                                ushort_t* __restrict__ dst){
  const float* W = (blockIdx.z == 0) ? W0 : (blockIdx.z == 1) ? W1 : (blockIdx.z == 2) ? W2 : W3;
  ushort_t* o = dst + (size_t)blockIdx.z * D_ * D_;
  __shared__ float t[32][33];
  int j = threadIdx.x & 31, i0 = threadIdx.x >> 5;
  int kb = blockIdx.y * 32, nb = blockIdx.x * 32;
#pragma unroll
  for (int r = 0; r < 4; r++){
    int i = i0 + r * 8;
    t[i][j] = W[(size_t)(kb + i) * D_ + nb + j];
  }
  __syncthreads();
#pragma unroll
  for (int r = 0; r < 4; r++){
    int i = i0 + r * 8;
    o[(size_t)(nb + i) * D_ + kb + j] = f2bf(t[j][i]);
  }
}

// ---------------- concat bq|bk|bv -> [2304] ----------------
__global__ __launch_bounds__(256) void k_bias3(const float* __restrict__ b0, const float* __restrict__ b1,
                                               const float* __restrict__ b2, float* __restrict__ o){
  int i = blockIdx.x * 256 + threadIdx.x;
  if (i < 3 * D_){
    float v = (i < D_) ? b0[i] : (i < 2 * D_) ? b1[i - D_] : b2[i - 2 * D_];
    o[i] = v;
  }
}

// ---------------- fused hs->bf16 convert + pooled-gate stage 1 ----------------
__global__ __launch_bounds__(256) void k_prep(const float* __restrict__ hs, const float* __restrict__ mask,
                                              ushort_t* __restrict__ hsb,
                                              float* __restrict__ partial, float* __restrict__ pcnt){
  int chunk = blockIdx.x, b = blockIdx.y, tid = threadIdx.x;
  const float* mrow = mask + b * S_ + chunk * 64;
  const float* base = hs + ((size_t)b * S_ + chunk * 64) * D_;
  ushort_t* obase = hsb + ((size_t)b * S_ + chunk * 64) * D_;
  float a0 = 0.f, a1 = 0.f, a2 = 0.f, cnt = 0.f;
#pragma unroll 2
  for (int s = 0; s < 64; s++){
    const float* r = base + (size_t)s * D_;
    float x0 = r[tid], x1 = r[tid + 256], x2 = r[tid + 512];
    ushort_t* o = obase + (size_t)s * D_;
    o[tid] = f2bf(x0); o[tid + 256] = f2bf(x1); o[tid + 512] = f2bf(x2);
    if (mrow[s] == 0.0f){ a0 += x0; a1 += x1; a2 += x2; cnt += 1.0f; }
  }
  float* o = partial + (size_t)(b * 8 + chunk) * D_;
  o[tid] = a0; o[tid + 256] = a1; o[tid + 512] = a2;
  if (tid == 0) pcnt[b * 8 + chunk] = cnt;
}

// ---------------- pooled gate, stage 2 ----------------
__global__ __launch_bounds__(256) void k_pool2(const float* __restrict__ partial, const float* __restrict__ pcnt,
                                               const float* __restrict__ Wg, const float* __restrict__ bg,
                                               float* __restrict__ gate){
  int b = blockIdx.x, tid = threadIdx.x;
  __shared__ float red[256];
  __shared__ float hp[768];
  float a0 = 0.f, a1 = 0.f, a2 = 0.f;
#pragma unroll
  for (int c = 0; c < 8; c++){
    const float* p = partial + (size_t)(b * 8 + c) * D_;
    a0 += p[tid]; a1 += p[tid + 256]; a2 += p[tid + 512];
  }
  float denom = 0.f;
#pragma unroll
  for (int c = 0; c < 8; c++) denom += pcnt[b * 8 + c];
  float inv = 1.0f / fmaxf(denom, 1.0f);
  hp[tid] = a0 * inv; hp[tid + 256] = a1 * inv; hp[tid + 512] = a2 * inv;
  __syncthreads();
  float p0 = 0.f, p1 = 0.f;
  for (int d = tid; d < D_; d += 256){ p0 += hp[d] * Wg[d * 2]; p1 += hp[d] * Wg[d * 2 + 1]; }
  red[tid] = p0; __syncthreads();
  for (int o = 128; o > 0; o >>= 1){ if (tid < o) red[tid] += red[tid + o]; __syncthreads(); }
  float z0 = red[0]; __syncthreads();
  red[tid] = p1; __syncthreads();
  for (int o = 128; o > 0; o >>= 1){ if (tid < o) red[tid] += red[tid + o]; __syncthreads(); }
  float z1 = red[0];
  if (tid == 0){
    z0 = (z0 + bg[0]) * 0.5f; z1 = (z1 + bg[1]) * 0.5f;
    float m = fmaxf(z0, z1);
    float e0 = __expf(z0 - m), e1 = __expf(z1 - m);
    float ssum = e0 + e1;
    gate[b * 2] = e0 / ssum; gate[b * 2 + 1] = e1 / ssum;
  }
}

// ---------------- BT GEMM (128x128 tile, BK=64, swizzled LDS, global_load_lds) ----------
// MAP 0: (bx=n, by=m, bz=z) | MAP 1: (bx=m, by=n) XCD-local same-m | MAP 2: (bx=z, by=m, bz=n).
template<int OUTBF16, int RELU, int RESID, int AFP32, int MAP>
__global__ __launch_bounds__(256) void k_gemm_bt(
    const void* __restrict__ Ap, long sA, int lda,
    const ushort_t* __restrict__ Bm, long sB, int ldb,
    void* __restrict__ Cp, long sC, int ldc,
    const float* __restrict__ bias,
    const float* __restrict__ resid, float alpha, int K)
{
  __shared__ ushort_t As[128 * 64];
  __shared__ ushort_t Bs[128 * 64];
  int z, bm, bn;
  if (MAP == 2){ z = blockIdx.x; bm = blockIdx.y; bn = blockIdx.z; }
  else if (MAP == 1){ z = blockIdx.z; bm = blockIdx.x; bn = blockIdx.y; }
  else { z = blockIdx.z; bm = blockIdx.y; bn = blockIdx.x; }
  const ushort_t* Ab = AFP32 ? nullptr : ((const ushort_t*)Ap + (size_t)z * sA);
  const float*    Af = AFP32 ? ((const float*)Ap + (size_t)z * sA) : nullptr;
  const ushort_t* Bb = Bm + (size_t)z * sB;
  const long coff = (long)z * sC;
  const int tid = threadIdx.x;
  const int m0 = bm * 128, n0 = bn * 128;
  const int wid = tid >> 6, lane = tid & 63;
  const int quad = lane >> 4, l16 = lane & 15;
  const int wm = wid >> 1, wn = wid & 1;
  const int sw = l16 & 7;                 // fragment-read swizzle (row-local)

  f32x4 acc[4][4];
#pragma unroll
  for (int i = 0; i < 4; i++)
#pragma unroll
    for (int j = 0; j < 4; j++) acc[i][j] = (f32x4){0.f, 0.f, 0.f, 0.f};

  for (int k0 = 0; k0 < K; k0 += 64){
#pragma unroll
    for (int c = 0; c < 4; c++){
      int idx = tid + c * 256;            // 1024 chunks: row = idx>>3, pos = idx&7
      int row = idx >> 3, p = idx & 7;
      int cg = p ^ (row & 7);
      if (AFP32){
        const float* src = Af + (size_t)(m0 + row) * lda + k0 + cg * 8;
        float4 f0 = *(const float4*)src;
        float4 f1 = *(const float4*)(src + 4);
        uint4 pk;
        pk.x = pack2(f0.x, f0.y);
        pk.y = pack2(f0.z, f0.w);
        pk.z = pack2(f1.x, f1.y);
        pk.w = pack2(f1.z, f1.w);
        *(uint4*)(&As[idx * 8]) = pk;
      } else {
        gld16(Ab + (size_t)(m0 + row) * lda + k0 + cg * 8, &As[idx * 8]);
      }
    }
#pragma unroll
    for (int c = 0; c < 4; c++){
      int idx = tid + c * 256;
      int row = idx >> 3, p = idx & 7;
      int cg = p ^ (row & 7);
      gld16(Bb + (size_t)(n0 + row) * ldb + k0 + cg * 8, &Bs[idx * 8]);
    }
    __syncthreads();
#pragma unroll
    for (int ks = 0; ks < 2; ks++){
      bf16x8 af[4], bfv[4];
#pragma unroll
      for (int mi = 0; mi < 4; mi++){
        int row = wm * 64 + mi * 16 + l16;
        af[mi] = *(const bf16x8*)(&As[(row * 8 + ((ks * 4 + quad) ^ sw)) * 8]);
      }
#pragma unroll
      for (int ni = 0; ni < 4; ni++){
        int row = wn * 64 + ni * 16 + l16;
        bfv[ni] = *(const bf16x8*)(&Bs[(row * 8 + ((ks * 4 + quad) ^ sw)) * 8]);
      }
#pragma unroll
      for (int mi = 0; mi < 4; mi++)
#pragma unroll
        for (int ni = 0; ni < 4; ni++)
          acc[mi][ni] = __builtin_amdgcn_mfma_f32_16x16x32_bf16(af[mi], bfv[ni], acc[mi][ni], 0, 0, 0);
    }
    __syncthreads();
  }

#pragma unroll
  for (int mi = 0; mi < 4; mi++){
#pragma unroll
    for (int ni = 0; ni < 4; ni++){
      int col = n0 + wn * 64 + ni * 16 + l16;
      float bcol = bias ? bias[col] : 0.0f;
#pragma unroll
      for (int r = 0; r < 4; r++){
        int row = m0 + wm * 64 + mi * 16 + quad * 4 + r;
        float v = acc[mi][ni][r] * alpha + bcol;
        if (RELU) v = fmaxf(v, 0.0f);
        if (RESID) v += resid[(size_t)row * ldc + col];
        long idx = coff + (long)row * ldc + col;
        if (OUTBF16) ((ushort_t*)Cp)[idx] = f2bf(v);
        else         ((float*)Cp)[idx] = v;
      }
    }
  }
}

// ---------------- per-head V transpose: vt[z][dh][t] = v[b,t,(voff)+h*64+dh] ----------------
__global__ __launch_bounds__(256) void k_vtrans(const ushort_t* __restrict__ v, int ldv,
                                                ushort_t* __restrict__ vt){
  __shared__ ushort_t t[64][66];
  int st = blockIdx.x * 64; int z = blockIdx.y;
  int b = z / H_, h = z - b * H_;
  int tid = threadIdx.x;
  const ushort_t* src = v + ((size_t)b * S_ + st) * ldv + h * DH_;
#pragma unroll
  for (int rep = 0; rep < 8; rep++){
    int idx = rep * 256 + tid;
    int i = idx >> 5, u = idx & 31;
    unsigned int val = *(const unsigned int*)(src + (size_t)i * ldv + u * 2);
    *(unsigned int*)(&t[i][u * 2]) = val;
  }
  __syncthreads();
  ushort_t* dst = vt + (size_t)z * DH_ * S_ + st;
#pragma unroll
  for (int rep = 0; rep < 8; rep++){
    int idx = rep * 256 + tid;
    int d = idx >> 5, u2 = idx & 31;
    unsigned int val = (unsigned int)t[u2 * 2][d] | ((unsigned int)t[u2 * 2 + 1][d] << 16);
    *(unsigned int*)(dst + (size_t)d * S_ + u2 * 2) = val;
  }
}

// ---------------- fused flash attention with prior blend ----------------
// R8 compute structure, three occupancy/staging upgrades:
//  - Q fragments loop-invariant in registers (Qs LDS buffer deleted)
//  - Ks/Vs staged via global_load_lds with XOR chunk swizzle (unpadded, conflict-free)
//  - LDS 63 -> ~50 KB => 3 blocks/CU
__global__ __launch_bounds__(256) void k_flash(
    const ushort_t* __restrict__ qkv,      // [B*S][2304]; q at col 0, k at col 768
    const ushort_t* __restrict__ vt,       // [B*H][64][512]
    const ushort_t* __restrict__ priorctx, // [B*S][768] bf16
    const float* __restrict__ mask,        // [B][S]
    const float* __restrict__ gate,        // [B][2]
    ushort_t* __restrict__ ctx)            // [B*S][768]
{
  __shared__ ushort_t Ks[KT_ * 64];    // [t][dh], XOR-swizzled 16B chunks
  __shared__ ushort_t Vs[DH_ * 128];   // [dh][t], XOR-swizzled 16B chunks
  __shared__ ushort_t Ps[QT_ * 136];   // [q][t], padded stride 136 (16B-aligned rows)
  __shared__ float rs[QT_];
  const int z = blockIdx.x, b = z / H_, h = z - b * H_;
  const int q0 = blockIdx.y * QT_;
  const int tid = threadIdx.x;
  const int wid = tid >> 6, lane = tid & 63, quad = lane >> 4, l16 = lane & 15;

  // Q fragments (loop-invariant): B-operand rows q = ni*16+l16, k = ks*32+quad*8
  bf16x8 bq[4][2];
#pragma unroll
  for (int ni = 0; ni < 4; ni++)
#pragma unroll
    for (int ks = 0; ks < 2; ks++)
      bq[ni][ks] = *(const bf16x8*)(qkv + ((size_t)(b * S_ + q0 + ni * 16 + l16)) * 2304
                                    + h * DH_ + ks * 32 + quad * 8);
  if (tid < QT_) rs[tid] = 0.f;

  f32x4 accv[4];
#pragma unroll
  for (int ni = 0; ni < 4; ni++) accv[ni] = (f32x4){0.f, 0.f, 0.f, 0.f};

  for (int t0 = 0; t0 < S_; t0 += KT_){
    if (mask[b * S_ + t0] != 0.0f) break;   // monotone pad mask: whole tile masked
    // stage K tile (128 rows x 8 chunks) and V^T tile (64 rows x 16 chunks), async
#pragma unroll
    for (int c = 0; c < 4; c++){
      int idx = tid + c * 256;
      int row = idx >> 3, p = idx & 7;
      int cg = p ^ (row & 7);
      gld16(qkv + ((size_t)(b * S_ + t0 + row)) * 2304 + D_ + h * DH_ + cg * 8, &Ks[idx * 8]);
    }
#pragma unroll
    for (int c = 0; c < 4; c++){
      int idx = tid + c * 256;
      int row = idx >> 4, p = idx & 15;
      int cg = p ^ (row & 15);
      gld16(vt + (size_t)z * (DH_ * S_) + (size_t)row * S_ + t0 + cg * 8, &Vs[idx * 8]);
    }
    __syncthreads();

    // S^T = K·Q^T : A from Ks (this wave's 32 t), B = Q regs; k-dim = dh (64)
    f32x4 accs[2][4];
#pragma unroll
    for (int mi = 0; mi < 2; mi++)
#pragma unroll
      for (int ni = 0; ni < 4; ni++) accs[mi][ni] = (f32x4){0.f, 0.f, 0.f, 0.f};
#pragma unroll
    for (int ks = 0; ks < 2; ks++){
      bf16x8 ak[2];
#pragma unroll
      for (int mi = 0; mi < 2; mi++){
        int row = wid * 32 + mi * 16 + l16;
        ak[mi] = *(const bf16x8*)(&Ks[(row * 8 + ((ks * 4 + quad) ^ (l16 & 7))) * 8]);
      }
#pragma unroll
      for (int mi = 0; mi < 2; mi++)
#pragma unroll
        for (int ni = 0; ni < 4; ni++)
          accs[mi][ni] = __builtin_amdgcn_mfma_f32_16x16x32_bf16(ak[mi], bq[ni][ks], accs[mi][ni], 0, 0, 0);
    }

    // exp + pack into Ps[q][t] + row sums
    float mv[2][4];
#pragma unroll
    for (int mi = 0; mi < 2; mi++)
#pragma unroll
      for (int r = 0; r < 4; r++)
        mv[mi][r] = mask[b * S_ + t0 + wid * 32 + mi * 16 + quad * 4 + r];
    float rowpart[4] = {0.f, 0.f, 0.f, 0.f};
#pragma unroll
    for (int mi = 0; mi < 2; mi++){
#pragma unroll
      for (int ni = 0; ni < 4; ni++){
        float e0 = __expf(accs[mi][ni][0] * 0.125f + mv[mi][0]);
        float e1 = __expf(accs[mi][ni][1] * 0.125f + mv[mi][1]);
        float e2 = __expf(accs[mi][ni][2] * 0.125f + mv[mi][2]);
        float e3 = __expf(accs[mi][ni][3] * 0.125f + mv[mi][3]);
        rowpart[ni] += (e0 + e1) + (e2 + e3);
        uint2 pk;
        pk.x = pack2(e0, e1);
        pk.y = pack2(e2, e3);
        *(uint2*)(&Ps[(ni * 16 + l16) * 136 + wid * 32 + mi * 16 + quad * 4]) = pk;
      }
    }
#pragma unroll
    for (int ni = 0; ni < 4; ni++){
      rowpart[ni] += __shfl_xor(rowpart[ni], 16);
      rowpart[ni] += __shfl_xor(rowpart[ni], 32);
    }
    if (lane < 16){
#pragma unroll
      for (int ni = 0; ni < 4; ni++) atomicAdd(&rs[ni * 16 + l16], rowpart[ni]);
    }
    __syncthreads();

    // PV: A = Ps (this wave's 16 q rows), B = Vs (dh), k = t (128)
#pragma unroll
    for (int ks = 0; ks < 4; ks++){
      bf16x8 ap = *(const bf16x8*)(&Ps[(wid * 16 + l16) * 136 + ks * 32 + quad * 8]);
#pragma unroll
      for (int ni = 0; ni < 4; ni++){
        bf16x8 bv8 = *(const bf16x8*)(&Vs[((ni * 16 + l16) * 16 + ((ks * 4 + quad) ^ l16)) * 8]);
        accv[ni] = __builtin_amdgcn_mfma_f32_16x16x32_bf16(ap, bv8, accv[ni], 0, 0, 0);
      }
    }
    __syncthreads();
  }

  const float g0 = gate[b * 2], g1 = gate[b * 2 + 1];
#pragma unroll
  for (int ni = 0; ni < 4; ni++){
#pragma unroll
    for (int r = 0; r < 4; r++){
      int q = wid * 16 + quad * 4 + r;
      int dh = ni * 16 + l16;
      float scl = g0 / rs[q];
      size_t idx = ((size_t)(b * S_ + q0 + q)) * D_ + h * DH_ + dh;
      float v = accv[ni][r] * scl + g1 * bf2f(priorctx[idx]);
      ctx[idx] = f2bf(v);
    }
  }
}

// ---------------- in-place LayerNorm over D=768 ----------------
__global__ __launch_bounds__(256) void k_ln(float* __restrict__ out, const float* __restrict__ gamma,
                                            const float* __restrict__ beta){
  __shared__ float red[256];
  int row = blockIdx.x, tid = threadIdx.x;
  float* p = out + (size_t)row * D_;
  float x0 = p[tid], x1 = p[tid + 256], x2 = p[tid + 512];
  red[tid] = x0 + x1 + x2; __syncthreads();
  for (int o = 128; o > 0; o >>= 1){ if (tid < o) red[tid] += red[tid + o]; __syncthreads(); }
  float mu = red[0] * (1.0f / 768.0f);
  __syncthreads();
  float d0 = x0 - mu, d1 = x1 - mu, d2 = x2 - mu;
  red[tid] = d0 * d0 + d1 * d1 + d2 * d2; __syncthreads();
  for (int o = 128; o > 0; o >>= 1){ if (tid < o) red[tid] += red[tid + o]; __syncthreads(); }
  float rsv = rsqrtf(red[0] * (1.0f / 768.0f) + 1e-5f);
  p[tid]       = d0 * rsv * gamma[tid]       + beta[tid];
  p[tid + 256] = d1 * rsv * gamma[tid + 256] + beta[tid + 256];
  p[tid + 512] = d2 * rsv * gamma[tid + 512] + beta[tid + 512];
}

extern "C" void kernel_launch(void* const* d_in, const int* in_sizes, int n_in,
                              void* d_out, int out_size, void* d_ws, size_t ws_size,
                              hipStream_t stream){
  const float* hs    = (const float*)d_in[0];
  const float* mask  = (const float*)d_in[1];
  const float* prior = (const float*)d_in[2];
  const float* Wq = (const float*)d_in[3];  const float* bq = (const float*)d_in[4];
  const float* Wk = (const float*)d_in[5];  const float* bk = (const float*)d_in[6];
  const float* Wv = (const float*)d_in[7];  const float* bv = (const float*)d_in[8];
  const float* Wg = (const float*)d_in[9];  const float* bg = (const float*)d_in[10];
  const float* Wo = (const float*)d_in[11]; const float* bo = (const float*)d_in[12];
  const float* gamma = (const float*)d_in[13]; const float* beta = (const float*)d_in[14];
  float* out = (float*)d_out;

  size_t off = 0;
  auto alloc = [&](size_t bytes) -> char* {
    char* p = (char*)d_ws + off;
    off += (bytes + 255) & ~(size_t)255;
    return p;
  };
  const size_t HSD = (size_t)NB_ * S_ * D_;            // 6.29M elems
  ushort_t* hsb     = (ushort_t*)alloc(HSD * 2);
  ushort_t* qkvb    = (ushort_t*)alloc(HSD * 3 * 2);   // [B*S][2304]
  ushort_t* vtb     = (ushort_t*)alloc(HSD * 2);       // [B*H][64][512]
  ushort_t* wt      = (ushort_t*)alloc((size_t)4 * D_ * D_ * 2);
  ushort_t* priorctx= (ushort_t*)alloc(HSD * 2);
  ushort_t* ctx     = (ushort_t*)alloc(HSD * 2);
  float*    bqkv    = (float*)alloc((size_t)3 * D_ * 4);
  float*    gate    = (float*)alloc(256);
  float*    partial = (float*)alloc((size_t)NB_ * 8 * D_ * 4);
  float*    pcnt    = (float*)alloc((size_t)NB_ * 8 * 4);

  // 1. converts / packs (hs convert fused with pool stage-1)
  k_prep<<<dim3(8, NB_), 256, 0, stream>>>(hs, mask, hsb, partial, pcnt);
  k_wtrans<<<dim3(24, 24, 4), 256, 0, stream>>>(Wq, Wk, Wv, Wo, wt);
  k_bias3<<<dim3(9), 256, 0, stream>>>(bq, bk, bv, bqkv);
  // 2. gate
  k_pool2<<<dim3(NB_), 256, 0, stream>>>(partial, pcnt, Wg, bg, gate);
  // 3. fused QKV projection: [8192x768] x [2304x768]^T -> [8192][2304] (MAP1: same-m -> same XCD)
  k_gemm_bt<1, 0, 0, 0, 1><<<dim3(64, 18, 1), 256, 0, stream>>>(
      hsb, 0, D_, wt, 0, D_, qkvb, 0, 3 * D_, bqkv, nullptr, 1.0f, D_);
  // 4. V transpose per head (v at col 1536 of qkvb)
  k_vtrans<<<dim3(S_ / 64, NB_ * H_), 256, 0, stream>>>(qkvb + 2 * D_, 3 * D_, vtb);
  // 5. priorctx = prior @ V (MAP2: same-batch -> same XCD; fp32 prior staged direct)
  k_gemm_bt<1, 0, 0, 1, 2><<<dim3(16, 4, 6), 256, 0, stream>>>(
      prior, (long)S_ * S_, S_, vtb, (long)H_ * DH_ * S_, S_,
      priorctx, (long)S_ * D_, D_, nullptr, nullptr, 1.0f, S_);
  // 6. flash attention + prior blend -> ctx (bf16); grid x=z so same-z -> same XCD
  k_flash<<<dim3(NB_ * H_, S_ / QT_), 256, 0, stream>>>(
      qkvb, vtb, priorctx, mask, gate, ctx);
  // 7. out = relu(ctx·Wo + bo) + hs  (fp32 into d_out)
  k_gemm_bt<0, 1, 1, 0, 1><<<dim3(64, 6, 1), 256, 0, stream>>>(
      ctx, 0, D_, wt + 3 * (size_t)D_ * D_, 0, D_, out, 0, D_, bo, hs, 1.0f, D_);
  // 8. LayerNorm in place on d_out
  k_ln<<<dim3(NB_ * S_), 256, 0, stream>>>(out, gamma, beta);
}

// Round 10
// 274.595 us; speedup vs baseline: 1.4841x; 1.0619x over previous
//
#include <hip/hip_runtime.h>

#define NB_ 16   // batch
#define S_ 512
#define D_ 768
#define H_ 12
#define DH_ 64
#define QT_ 64   // flash q-tile
#define KT_ 128  // flash k-tile
#define LDQ_ 1536  // qkvb row stride (Q|K only; V diverted to vt)

typedef __attribute__((ext_vector_type(8))) short bf16x8;
typedef __attribute__((ext_vector_type(4))) float f32x4;
typedef unsigned short ushort_t;

__device__ __forceinline__ unsigned short f2bf(float f){
  unsigned int u = __float_as_uint(f);
  u += 0x7fffu + ((u >> 16) & 1u);   // round-to-nearest-even
  return (unsigned short)(u >> 16);
}
__device__ __forceinline__ float bf2f(unsigned short s){
  return __uint_as_float(((unsigned int)s) << 16);
}
__device__ __forceinline__ unsigned int pack2(float a, float b){
  return (unsigned int)f2bf(a) | ((unsigned int)f2bf(b) << 16);
}
// async global->LDS, 16B per lane. LDS side must be uniform-base + lane*16.
__device__ __forceinline__ void gld16(const ushort_t* g, ushort_t* l){
  __builtin_amdgcn_global_load_lds((const __attribute__((address_space(1))) unsigned int*)g,
                                   (__attribute__((address_space(3))) unsigned int*)l, 16, 0, 0);
}

// ---------------- fused setup: prep (512 blk) | wtrans (2304 blk) | bias3 (9 blk) ----------------
__global__ __launch_bounds__(256) void k_setup(
    const float* __restrict__ hs, const float* __restrict__ mask,
    const float* __restrict__ W0, const float* __restrict__ W1,
    const float* __restrict__ W2, const float* __restrict__ W3,
    const float* __restrict__ b0, const float* __restrict__ b1, const float* __restrict__ b2,
    ushort_t* __restrict__ hsb, ushort_t* __restrict__ wt, float* __restrict__ bqkv,
    float* __restrict__ partial, float* __restrict__ pcnt)
{
  __shared__ float t[32][33];
  const int bx = blockIdx.x, tid = threadIdx.x;
  if (bx < 512){
    // prep: 16 rows per block, 32 chunks per batch
    int chunk = bx & 31, b = bx >> 5;
    const float* mrow = mask + b * S_ + chunk * 16;
    const float* base = hs + ((size_t)b * S_ + chunk * 16) * D_;
    ushort_t* obase = hsb + ((size_t)b * S_ + chunk * 16) * D_;
    float a0 = 0.f, a1 = 0.f, a2 = 0.f, cnt = 0.f;
#pragma unroll 2
    for (int s = 0; s < 16; s++){
      const float* r = base + (size_t)s * D_;
      float x0 = r[tid], x1 = r[tid + 256], x2 = r[tid + 512];
      ushort_t* o = obase + (size_t)s * D_;
      o[tid] = f2bf(x0); o[tid + 256] = f2bf(x1); o[tid + 512] = f2bf(x2);
      if (mrow[s] == 0.0f){ a0 += x0; a1 += x1; a2 += x2; cnt += 1.0f; }
    }
    float* o = partial + (size_t)(b * 32 + chunk) * D_;
    o[tid] = a0; o[tid + 256] = a1; o[tid + 512] = a2;
    if (tid == 0) pcnt[b * 32 + chunk] = cnt;
  } else if (bx < 512 + 2304){
    // weight transpose fp32[K][N] -> bf16[N][K]
    int idx = bx - 512;
    int z = idx / 576, rem = idx - z * 576;
    int ky = rem / 24, nx = rem - ky * 24;
    const float* W = (z == 0) ? W0 : (z == 1) ? W1 : (z == 2) ? W2 : W3;
    ushort_t* o = wt + (size_t)z * D_ * D_;
    int j = tid & 31, i0 = tid >> 5;
    int kb = ky * 32, nb = nx * 32;
#pragma unroll
    for (int r = 0; r < 4; r++){
      int i = i0 + r * 8;
      t[i][j] = W[(size_t)(kb + i) * D_ + nb + j];
    }
    __syncthreads();
#pragma unroll
    for (int r = 0; r < 4; r++){
      int i = i0 + r * 8;
      o[(size_t)(nb + i) * D_ + kb + j] = f2bf(t[j][i]);
    }
  } else {
    int i = (bx - 2816) * 256 + tid;
    if (i < 3 * D_){
      float v = (i < D_) ? b0[i] : (i < 2 * D_) ? b1[i - D_] : b2[i - 2 * D_];
      bqkv[i] = v;
    }
  }
}

// ---------------- pooled gate, stage 2 (32 partials) ----------------
__global__ __launch_bounds__(256) void k_pool2(const float* __restrict__ partial, const float* __restrict__ pcnt,
                                               const float* __restrict__ Wg, const float* __restrict__ bg,
                                               float* __restrict__ gate){
  int b = blockIdx.x, tid = threadIdx.x;
  __shared__ float red[256];
  __shared__ float hp[768];
  float a0 = 0.f, a1 = 0.f, a2 = 0.f;
#pragma unroll
  for (int c = 0; c < 32; c++){
    const float* p = partial + (size_t)(b * 32 + c) * D_;
    a0 += p[tid]; a1 += p[tid + 256]; a2 += p[tid + 512];
  }
  float denom = 0.f;
#pragma unroll
  for (int c = 0; c < 32; c++) denom += pcnt[b * 32 + c];
  float inv = 1.0f / fmaxf(denom, 1.0f);
  hp[tid] = a0 * inv; hp[tid + 256] = a1 * inv; hp[tid + 512] = a2 * inv;
  __syncthreads();
  float p0 = 0.f, p1 = 0.f;
  for (int d = tid; d < D_; d += 256){ p0 += hp[d] * Wg[d * 2]; p1 += hp[d] * Wg[d * 2 + 1]; }
  red[tid] = p0; __syncthreads();
  for (int o = 128; o > 0; o >>= 1){ if (tid < o) red[tid] += red[tid + o]; __syncthreads(); }
  float z0 = red[0]; __syncthreads();
  red[tid] = p1; __syncthreads();
  for (int o = 128; o > 0; o >>= 1){ if (tid < o) red[tid] += red[tid + o]; __syncthreads(); }
  float z1 = red[0];
  if (tid == 0){
    z0 = (z0 + bg[0]) * 0.5f; z1 = (z1 + bg[1]) * 0.5f;
    float m = fmaxf(z0, z1);
    float e0 = __expf(z0 - m), e1 = __expf(z1 - m);
    float ssum = e0 + e1;
    gate[b * 2] = e0 / ssum; gate[b * 2 + 1] = e1 / ssum;
  }
}

// ---------------- BT GEMM (128x128 tile, BK=64, swizzled LDS, global_load_lds) ----------
// MAP 0: (bx=n, by=m, bz=z) | MAP 1: (bx=m, by=n) | MAP 2: (bx=z, by=m, bz=n).
// VSPLIT: n-tiles with n0 >= 1536 are V columns, written transposed to Cp2 = vt[z][dh][t].
template<int OUTBF16, int RELU, int RESID, int AFP32, int MAP, int VSPLIT>
__global__ __launch_bounds__(256) void k_gemm_bt(
    const void* __restrict__ Ap, long sA, int lda,
    const ushort_t* __restrict__ Bm, long sB, int ldb,
    void* __restrict__ Cp, long sC, int ldc, void* __restrict__ Cp2,
    const float* __restrict__ bias,
    const float* __restrict__ resid, float alpha, int K)
{
  __shared__ ushort_t As[128 * 64];
  __shared__ ushort_t Bs[128 * 64];
  int z, bm, bn;
  if (MAP == 2){ z = blockIdx.x; bm = blockIdx.y; bn = blockIdx.z; }
  else if (MAP == 1){ z = blockIdx.z; bm = blockIdx.x; bn = blockIdx.y; }
  else { z = blockIdx.z; bm = blockIdx.y; bn = blockIdx.x; }
  const ushort_t* Ab = AFP32 ? nullptr : ((const ushort_t*)Ap + (size_t)z * sA);
  const float*    Af = AFP32 ? ((const float*)Ap + (size_t)z * sA) : nullptr;
  const ushort_t* Bb = Bm + (size_t)z * sB;
  const long coff = (long)z * sC;
  const int tid = threadIdx.x;
  const int m0 = bm * 128, n0 = bn * 128;
  const int wid = tid >> 6, lane = tid & 63;
  const int quad = lane >> 4, l16 = lane & 15;
  const int wm = wid >> 1, wn = wid & 1;
  const int sw = l16 & 7;                 // fragment-read swizzle (row-local)

  f32x4 acc[4][4];
#pragma unroll
  for (int i = 0; i < 4; i++)
#pragma unroll
    for (int j = 0; j < 4; j++) acc[i][j] = (f32x4){0.f, 0.f, 0.f, 0.f};

  for (int k0 = 0; k0 < K; k0 += 64){
#pragma unroll
    for (int c = 0; c < 4; c++){
      int idx = tid + c * 256;            // 1024 chunks: row = idx>>3, pos = idx&7
      int row = idx >> 3, p = idx & 7;
      int cg = p ^ (row & 7);
      if (AFP32){
        const float* src = Af + (size_t)(m0 + row) * lda + k0 + cg * 8;
        float4 f0 = *(const float4*)src;
        float4 f1 = *(const float4*)(src + 4);
        uint4 pk;
        pk.x = pack2(f0.x, f0.y);
        pk.y = pack2(f0.z, f0.w);
        pk.z = pack2(f1.x, f1.y);
        pk.w = pack2(f1.z, f1.w);
        *(uint4*)(&As[idx * 8]) = pk;
      } else {
        gld16(Ab + (size_t)(m0 + row) * lda + k0 + cg * 8, &As[idx * 8]);
      }
    }
#pragma unroll
    for (int c = 0; c < 4; c++){
      int idx = tid + c * 256;
      int row = idx >> 3, p = idx & 7;
      int cg = p ^ (row & 7);
      gld16(Bb + (size_t)(n0 + row) * ldb + k0 + cg * 8, &Bs[idx * 8]);
    }
    __syncthreads();
#pragma unroll
    for (int ks = 0; ks < 2; ks++){
      bf16x8 af[4], bfv[4];
#pragma unroll
      for (int mi = 0; mi < 4; mi++){
        int row = wm * 64 + mi * 16 + l16;
        af[mi] = *(const bf16x8*)(&As[(row * 8 + ((ks * 4 + quad) ^ sw)) * 8]);
      }
#pragma unroll
      for (int ni = 0; ni < 4; ni++){
        int row = wn * 64 + ni * 16 + l16;
        bfv[ni] = *(const bf16x8*)(&Bs[(row * 8 + ((ks * 4 + quad) ^ sw)) * 8]);
      }
#pragma unroll
      for (int mi = 0; mi < 4; mi++)
#pragma unroll
        for (int ni = 0; ni < 4; ni++)
          acc[mi][ni] = __builtin_amdgcn_mfma_f32_16x16x32_bf16(af[mi], bfv[ni], acc[mi][ni], 0, 0, 0);
    }
    __syncthreads();
  }

  if (VSPLIT && n0 >= 1536){
    // V columns: write transposed into vt[z][dh][t]; 4 consecutive rows = 4 consecutive t
    ushort_t* vtp = (ushort_t*)Cp2;
    const int bb = m0 >> 9;             // batch (128-row tile never crosses a 512 boundary)
#pragma unroll
    for (int mi = 0; mi < 4; mi++){
#pragma unroll
      for (int ni = 0; ni < 4; ni++){
        int col = n0 + wn * 64 + ni * 16 + l16;
        float bcol = bias[col];
        int hh = (col - 1536) >> 6, dh = (col - 1536) & 63;
        int trow = (m0 & 511) + wm * 64 + mi * 16 + quad * 4;
        uint2 pk;
        pk.x = pack2(acc[mi][ni][0] + bcol, acc[mi][ni][1] + bcol);
        pk.y = pack2(acc[mi][ni][2] + bcol, acc[mi][ni][3] + bcol);
        *(uint2*)(vtp + ((size_t)(bb * H_ + hh) * DH_ + dh) * S_ + trow) = pk;
      }
    }
    return;
  }

#pragma unroll
  for (int mi = 0; mi < 4; mi++){
#pragma unroll
    for (int ni = 0; ni < 4; ni++){
      int col = n0 + wn * 64 + ni * 16 + l16;
      float bcol = bias ? bias[col] : 0.0f;
#pragma unroll
      for (int r = 0; r < 4; r++){
        int row = m0 + wm * 64 + mi * 16 + quad * 4 + r;
        float v = acc[mi][ni][r] * alpha + bcol;
        if (RELU) v = fmaxf(v, 0.0f);
        if (RESID) v += resid[(size_t)row * ldc + col];
        long idx = coff + (long)row * ldc + col;
        if (OUTBF16) ((ushort_t*)Cp)[idx] = f2bf(v);
        else         ((float*)Cp)[idx] = v;
      }
    }
  }
}

// ---------------- fused flash attention with prior blend ----------------
//  - Q fragments loop-invariant in registers
//  - Ks/Vs staged via global_load_lds with XOR chunk swizzle
//  - grid (x=z, y=qtile): same-z blocks share an XCD L2; monotone-mask tail-skip
__global__ __launch_bounds__(256) void k_flash(
    const ushort_t* __restrict__ qkv,      // [B*S][1536]; q at col 0, k at col 768
    const ushort_t* __restrict__ vt,       // [B*H][64][512]
    const ushort_t* __restrict__ priorctx, // [B*S][768] bf16
    const float* __restrict__ mask,        // [B][S]
    const float* __restrict__ gate,        // [B][2]
    ushort_t* __restrict__ ctx)            // [B*S][768]
{
  __shared__ ushort_t Ks[KT_ * 64];    // [t][dh], XOR-swizzled 16B chunks
  __shared__ ushort_t Vs[DH_ * 128];   // [dh][t], XOR-swizzled 16B chunks
  __shared__ ushort_t Ps[QT_ * 136];   // [q][t], padded stride 136
  __shared__ float rs[QT_];
  const int z = blockIdx.x, b = z / H_, h = z - b * H_;
  const int q0 = blockIdx.y * QT_;
  const int tid = threadIdx.x;
  const int wid = tid >> 6, lane = tid & 63, quad = lane >> 4, l16 = lane & 15;

  // Q fragments (loop-invariant): B-operand rows q = ni*16+l16, k = ks*32+quad*8
  bf16x8 bq[4][2];
#pragma unroll
  for (int ni = 0; ni < 4; ni++)
#pragma unroll
    for (int ks = 0; ks < 2; ks++)
      bq[ni][ks] = *(const bf16x8*)(qkv + ((size_t)(b * S_ + q0 + ni * 16 + l16)) * LDQ_
                                    + h * DH_ + ks * 32 + quad * 8);
  if (tid < QT_) rs[tid] = 0.f;

  f32x4 accv[4];
#pragma unroll
  for (int ni = 0; ni < 4; ni++) accv[ni] = (f32x4){0.f, 0.f, 0.f, 0.f};

  for (int t0 = 0; t0 < S_; t0 += KT_){
    if (mask[b * S_ + t0] != 0.0f) break;   // monotone pad mask: whole tile masked
    // stage K tile (128 rows x 8 chunks) and V^T tile (64 rows x 16 chunks), async
#pragma unroll
    for (int c = 0; c < 4; c++){
      int idx = tid + c * 256;
      int row = idx >> 3, p = idx & 7;
      int cg = p ^ (row & 7);
      gld16(qkv + ((size_t)(b * S_ + t0 + row)) * LDQ_ + D_ + h * DH_ + cg * 8, &Ks[idx * 8]);
    }
#pragma unroll
    for (int c = 0; c < 4; c++){
      int idx = tid + c * 256;
      int row = idx >> 4, p = idx & 15;
      int cg = p ^ (row & 15);
      gld16(vt + (size_t)z * (DH_ * S_) + (size_t)row * S_ + t0 + cg * 8, &Vs[idx * 8]);
    }
    __syncthreads();

    // S^T = K·Q^T : A from Ks (this wave's 32 t), B = Q regs; k-dim = dh (64)
    f32x4 accs[2][4];
#pragma unroll
    for (int mi = 0; mi < 2; mi++)
#pragma unroll
      for (int ni = 0; ni < 4; ni++) accs[mi][ni] = (f32x4){0.f, 0.f, 0.f, 0.f};
#pragma unroll
    for (int ks = 0; ks < 2; ks++){
      bf16x8 ak[2];
#pragma unroll
      for (int mi = 0; mi < 2; mi++){
        int row = wid * 32 + mi * 16 + l16;
        ak[mi] = *(const bf16x8*)(&Ks[(row * 8 + ((ks * 4 + quad) ^ (l16 & 7))) * 8]);
      }
#pragma unroll
      for (int mi = 0; mi < 2; mi++)
#pragma unroll
        for (int ni = 0; ni < 4; ni++)
          accs[mi][ni] = __builtin_amdgcn_mfma_f32_16x16x32_bf16(ak[mi], bq[ni][ks], accs[mi][ni], 0, 0, 0);
    }

    // exp + pack into Ps[q][t] + row sums
    float mv[2][4];
#pragma unroll
    for (int mi = 0; mi < 2; mi++)
#pragma unroll
      for (int r = 0; r < 4; r++)
        mv[mi][r] = mask[b * S_ + t0 + wid * 32 + mi * 16 + quad * 4 + r];
    float rowpart[4] = {0.f, 0.f, 0.f, 0.f};
#pragma unroll
    for (int mi = 0; mi < 2; mi++){
#pragma unroll
      for (int ni = 0; ni < 4; ni++){
        float e0 = __expf(accs[mi][ni][0] * 0.125f + mv[mi][0]);
        float e1 = __expf(accs[mi][ni][1] * 0.125f + mv[mi][1]);
        float e2 = __expf(accs[mi][ni][2] * 0.125f + mv[mi][2]);
        float e3 = __expf(accs[mi][ni][3] * 0.125f + mv[mi][3]);
        rowpart[ni] += (e0 + e1) + (e2 + e3);
        uint2 pk;
        pk.x = pack2(e0, e1);
        pk.y = pack2(e2, e3);
        *(uint2*)(&Ps[(ni * 16 + l16) * 136 + wid * 32 + mi * 16 + quad * 4]) = pk;
      }
    }
#pragma unroll
    for (int ni = 0; ni < 4; ni++){
      rowpart[ni] += __shfl_xor(rowpart[ni], 16);
      rowpart[ni] += __shfl_xor(rowpart[ni], 32);
    }
    if (lane < 16){
#pragma unroll
      for (int ni = 0; ni < 4; ni++) atomicAdd(&rs[ni * 16 + l16], rowpart[ni]);
    }
    __syncthreads();

    // PV: A = Ps (this wave's 16 q rows), B = Vs (dh), k = t (128)
#pragma unroll
    for (int ks = 0; ks < 4; ks++){
      bf16x8 ap = *(const bf16x8*)(&Ps[(wid * 16 + l16) * 136 + ks * 32 + quad * 8]);
#pragma unroll
      for (int ni = 0; ni < 4; ni++){
        bf16x8 bv8 = *(const bf16x8*)(&Vs[((ni * 16 + l16) * 16 + ((ks * 4 + quad) ^ l16)) * 8]);
        accv[ni] = __builtin_amdgcn_mfma_f32_16x16x32_bf16(ap, bv8, accv[ni], 0, 0, 0);
      }
    }
    __syncthreads();
  }

  const float g0 = gate[b * 2], g1 = gate[b * 2 + 1];
#pragma unroll
  for (int ni = 0; ni < 4; ni++){
#pragma unroll
    for (int r = 0; r < 4; r++){
      int q = wid * 16 + quad * 4 + r;
      int dh = ni * 16 + l16;
      float scl = g0 / rs[q];
      size_t idx = ((size_t)(b * S_ + q0 + q)) * D_ + h * DH_ + dh;
      float v = accv[ni][r] * scl + g1 * bf2f(priorctx[idx]);
      ctx[idx] = f2bf(v);
    }
  }
}

// ---------------- in-place LayerNorm over D=768 ----------------
__global__ __launch_bounds__(256) void k_ln(float* __restrict__ out, const float* __restrict__ gamma,
                                            const float* __restrict__ beta){
  __shared__ float red[256];
  int row = blockIdx.x, tid = threadIdx.x;
  float* p = out + (size_t)row * D_;
  float x0 = p[tid], x1 = p[tid + 256], x2 = p[tid + 512];
  red[tid] = x0 + x1 + x2; __syncthreads();
  for (int o = 128; o > 0; o >>= 1){ if (tid < o) red[tid] += red[tid + o]; __syncthreads(); }
  float mu = red[0] * (1.0f / 768.0f);
  __syncthreads();
  float d0 = x0 - mu, d1 = x1 - mu, d2 = x2 - mu;
  red[tid] = d0 * d0 + d1 * d1 + d2 * d2; __syncthreads();
  for (int o = 128; o > 0; o >>= 1){ if (tid < o) red[tid] += red[tid + o]; __syncthreads(); }
  float rsv = rsqrtf(red[0] * (1.0f / 768.0f) + 1e-5f);
  p[tid]       = d0 * rsv * gamma[tid]       + beta[tid];
  p[tid + 256] = d1 * rsv * gamma[tid + 256] + beta[tid + 256];
  p[tid + 512] = d2 * rsv * gamma[tid + 512] + beta[tid + 512];
}

extern "C" void kernel_launch(void* const* d_in, const int* in_sizes, int n_in,
                              void* d_out, int out_size, void* d_ws, size_t ws_size,
                              hipStream_t stream){
  const float* hs    = (const float*)d_in[0];
  const float* mask  = (const float*)d_in[1];
  const float* prior = (const float*)d_in[2];
  const float* Wq = (const float*)d_in[3];  const float* bq = (const float*)d_in[4];
  const float* Wk = (const float*)d_in[5];  const float* bk = (const float*)d_in[6];
  const float* Wv = (const float*)d_in[7];  const float* bv = (const float*)d_in[8];
  const float* Wg = (const float*)d_in[9];  const float* bg = (const float*)d_in[10];
  const float* Wo = (const float*)d_in[11]; const float* bo = (const float*)d_in[12];
  const float* gamma = (const float*)d_in[13]; const float* beta = (const float*)d_in[14];
  float* out = (float*)d_out;

  size_t off = 0;
  auto alloc = [&](size_t bytes) -> char* {
    char* p = (char*)d_ws + off;
    off += (bytes + 255) & ~(size_t)255;
    return p;
  };
  const size_t HSD = (size_t)NB_ * S_ * D_;            // 6.29M elems
  ushort_t* hsb     = (ushort_t*)alloc(HSD * 2);
  ushort_t* qkvb    = (ushort_t*)alloc(HSD * 2 * 2);   // [B*S][1536] (Q|K)
  ushort_t* vtb     = (ushort_t*)alloc(HSD * 2);       // [B*H][64][512]
  ushort_t* wt      = (ushort_t*)alloc((size_t)4 * D_ * D_ * 2);
  ushort_t* priorctx= (ushort_t*)alloc(HSD * 2);
  ushort_t* ctx     = (ushort_t*)alloc(HSD * 2);
  float*    bqkv    = (float*)alloc((size_t)3 * D_ * 4);
  float*    gate    = (float*)alloc(256);
  float*    partial = (float*)alloc((size_t)NB_ * 32 * D_ * 4);
  float*    pcnt    = (float*)alloc((size_t)NB_ * 32 * 4);

  // 1. fused setup: hs->bf16 + pool partials | weight transpose | bias concat
  k_setup<<<dim3(2825), 256, 0, stream>>>(hs, mask, Wq, Wk, Wv, Wo, bq, bk, bv,
                                          hsb, wt, bqkv, partial, pcnt);
  // 2. gate
  k_pool2<<<dim3(NB_), 256, 0, stream>>>(partial, pcnt, Wg, bg, gate);
  // 3. fused QKV projection (MAP1; V n-tiles written transposed into vtb)
  k_gemm_bt<1, 0, 0, 0, 1, 1><<<dim3(64, 18, 1), 256, 0, stream>>>(
      hsb, 0, D_, wt, 0, D_, qkvb, 0, LDQ_, vtb, bqkv, nullptr, 1.0f, D_);
  // 4. priorctx = prior @ V (MAP2: same-batch -> same XCD; fp32 prior staged direct)
  k_gemm_bt<1, 0, 0, 1, 2, 0><<<dim3(16, 4, 6), 256, 0, stream>>>(
      prior, (long)S_ * S_, S_, vtb, (long)H_ * DH_ * S_, S_,
      priorctx, (long)S_ * D_, D_, nullptr, nullptr, nullptr, 1.0f, S_);
  // 5. flash attention + prior blend -> ctx (bf16); grid x=z so same-z -> same XCD
  k_flash<<<dim3(NB_ * H_, S_ / QT_), 256, 0, stream>>>(
      qkvb, vtb, priorctx, mask, gate, ctx);
  // 6. out = relu(ctx·Wo + bo) + hs  (fp32 into d_out)
  k_gemm_bt<0, 1, 1, 0, 1, 0><<<dim3(64, 6, 1), 256, 0, stream>>>(
      ctx, 0, D_, wt + 3 * (size_t)D_ * D_, 0, D_, out, 0, D_, nullptr, bo, hs, 1.0f, D_);
  // 7. LayerNorm in place on d_out
  k_ln<<<dim3(NB_ * S_), 256, 0, stream>>>(out, gamma, beta);
}